// Round 1
// baseline (1730.691 us; speedup 1.0000x reference)
//
#include <hip/hip_runtime.h>
#include <math.h>

// Problem constants
#define BN   8
#define SN   2048
#define HN   1024
#define NTOK 16384   // B*S
#define NHD  16
#define HDD  64
#define NSD  64

// ---------------------------------------------------------------------------
// GEMM: C(NTOK x MCOLS) = A(NTOK x 1024) * W(1024 x MCOLS)
// MODE 0: plain store to out0.
// MODE 1: cols [0,1024) -> out0 (x_path); cols [1024,2048) -> silu -> out1.
// 128x128 tile, BK=16, 256 threads, 8x8 per thread.
// ---------------------------------------------------------------------------
template<int MCOLS, int MODE>
__global__ __launch_bounds__(256)
void sgemm128(const float* __restrict__ A, const float* __restrict__ W,
              float* __restrict__ out0, float* __restrict__ out1)
{
    __shared__ float As[16 * 132];   // transposed A tile [k][m], padded
    __shared__ float Bs[16 * 128];   // B tile [k][n]
    const int tid  = threadIdx.x;
    const int row0 = blockIdx.y * 128;
    const int col0 = blockIdx.x * 128;
    const int tx   = tid & 15, ty = tid >> 4;

    float acc[8][8];
#pragma unroll
    for (int i = 0; i < 8; ++i)
#pragma unroll
        for (int j = 0; j < 8; ++j) acc[i][j] = 0.f;

    const int a_col4 = tid & 3;    // which float4 in the 16-wide K slab
    const int a_row  = tid >> 2;   // 0..63
    const int b_col4 = tid & 31;   // 0..31
    const int b_row  = tid >> 5;   // 0..7

    for (int bk = 0; bk < 1024; bk += 16) {
#pragma unroll
        for (int s = 0; s < 2; ++s) {
            const int r = a_row + s * 64;
            const float4 v = *(const float4*)&A[(size_t)(row0 + r) * 1024 + bk + a_col4 * 4];
            As[(a_col4 * 4 + 0) * 132 + r] = v.x;
            As[(a_col4 * 4 + 1) * 132 + r] = v.y;
            As[(a_col4 * 4 + 2) * 132 + r] = v.z;
            As[(a_col4 * 4 + 3) * 132 + r] = v.w;
        }
#pragma unroll
        for (int s = 0; s < 2; ++s) {
            const int r = b_row + s * 8;
            *(float4*)&Bs[r * 128 + b_col4 * 4] =
                *(const float4*)&W[(size_t)(bk + r) * MCOLS + col0 + b_col4 * 4];
        }
        __syncthreads();
#pragma unroll
        for (int k = 0; k < 16; ++k) {
            float a[8], b[8];
            *(float4*)&a[0] = *(const float4*)&As[k * 132 + ty * 8];
            *(float4*)&a[4] = *(const float4*)&As[k * 132 + ty * 8 + 4];
            *(float4*)&b[0] = *(const float4*)&Bs[k * 128 + tx * 8];
            *(float4*)&b[4] = *(const float4*)&Bs[k * 128 + tx * 8 + 4];
#pragma unroll
            for (int i = 0; i < 8; ++i)
#pragma unroll
                for (int j = 0; j < 8; ++j) acc[i][j] += a[i] * b[j];
        }
        __syncthreads();
    }

#pragma unroll
    for (int i = 0; i < 8; ++i) {
        const int r = row0 + ty * 8 + i;
        const int c = col0 + tx * 8;
        if (MODE == 0) {
            *(float4*)&out0[(size_t)r * MCOLS + c]     = *(float4*)&acc[i][0];
            *(float4*)&out0[(size_t)r * MCOLS + c + 4] = *(float4*)&acc[i][4];
        } else {
            if (c < 1024) {   // uniform per block (128-col tiles don't straddle)
                *(float4*)&out0[(size_t)r * 1024 + c]     = *(float4*)&acc[i][0];
                *(float4*)&out0[(size_t)r * 1024 + c + 4] = *(float4*)&acc[i][4];
            } else {
#pragma unroll
                for (int j = 0; j < 8; ++j) {
                    const float z = acc[i][j];
                    out1[(size_t)r * 1024 + (c - 1024) + j] = z / (1.f + expf(-z));
                }
            }
        }
    }
}

// ---------------------------------------------------------------------------
// Depthwise causal conv (K=4, left pad 3) + bias + silu.
// x_path (B,S,H) -> xh (B,S,H)  [xh is also the (B,S,NH,HD) view]
// ---------------------------------------------------------------------------
__global__ __launch_bounds__(256)
void conv_silu(const float* __restrict__ xp, const float* __restrict__ cw,
               const float* __restrict__ cb, float* __restrict__ xh)
{
    const int idx = blockIdx.x * 256 + threadIdx.x;      // NTOK*HN total
    const int c  = idx & 1023;
    const int bt = idx >> 10;
    const int t  = bt & (SN - 1);
    float acc = cb[c];
#pragma unroll
    for (int k = 0; k < 4; ++k) {
        const int tt = t - 3 + k;
        if (tt >= 0)
            acc += cw[c * 4 + k] * xp[((size_t)(bt - 3 + k) << 10) + c];
    }
    xh[(size_t)idx] = acc / (1.f + expf(-acc));
}

// ---------------------------------------------------------------------------
// Backbone: per token-head th (=(b,s,nh)):
//   bb = silu(xh@bb_w + bb_b); f1=tanh(bb@f1_w+f1_b); f2=tanh(bb@f2_w+f2_b)
//   tau=sigmoid(bb@tau_a_w+tau_a_b+tau_b); dec=sigmoid(bb@decay_w+decay_b)
//   cand = f1*(1-tau)+f2*tau
// All 5 64x64 weight matrices staged in LDS (80KB). 32 token-heads / round,
// 4 rounds / block, thread = (group g=tid>>6 owning 8 th's, column j=tid&63).
// ---------------------------------------------------------------------------
__global__ __launch_bounds__(256)
void backbone(const float* __restrict__ xh,
              const float* __restrict__ bbw, const float* __restrict__ bbb,
              const float* __restrict__ f1w, const float* __restrict__ f1b,
              const float* __restrict__ f2w, const float* __restrict__ f2b,
              const float* __restrict__ tauw, const float* __restrict__ taub,
              const float* __restrict__ taub2,
              const float* __restrict__ decw, const float* __restrict__ decb,
              float* __restrict__ cand, float* __restrict__ decay)
{
    __shared__ float wl[5 * 4096];       // bb | f1 | f2 | tau | dec
    __shared__ float xs[32 * 64];
    __shared__ float bs[32 * 64];
    const int tid = threadIdx.x;

    // stage all weights once (1024 float4 per matrix)
    for (int i = tid; i < 1024; i += 256) {
        ((float4*)(wl        ))[i] = ((const float4*)bbw )[i];
        ((float4*)(wl +  4096))[i] = ((const float4*)f1w )[i];
        ((float4*)(wl +  8192))[i] = ((const float4*)f2w )[i];
        ((float4*)(wl + 12288))[i] = ((const float4*)tauw)[i];
        ((float4*)(wl + 16384))[i] = ((const float4*)decw)[i];
    }
    __syncthreads();

    const int j = tid & 63, grp = tid >> 6;

    for (int r = 0; r < 4; ++r) {
        const int base = (blockIdx.x * 4 + r) * 32;   // first token-head
        // stage xh[base..base+32)[0..64) : 512 float4
        for (int i = tid; i < 512; i += 256)
            ((float4*)xs)[i] = ((const float4*)(xh + (size_t)base * 64))[i];
        __syncthreads();

        // phase 1: bb
        float a0[8];
#pragma unroll
        for (int g = 0; g < 8; ++g) a0[g] = bbb[j];
#pragma unroll 4
        for (int i = 0; i < 64; ++i) {
            const float w = wl[i * 64 + j];
#pragma unroll
            for (int g = 0; g < 8; ++g) a0[g] += xs[(grp * 8 + g) * 64 + i] * w;
        }
#pragma unroll
        for (int g = 0; g < 8; ++g) {
            const float v = a0[g];
            bs[(grp * 8 + g) * 64 + j] = v / (1.f + expf(-v));
        }
        __syncthreads();

        // phase 2: f1,f2,tau,dec
        float A1[8], A2[8], A3[8], A4[8];
        const float b1 = f1b[j], b2 = f2b[j], b3 = taub[j] + taub2[j], b4 = decb[j];
#pragma unroll
        for (int g = 0; g < 8; ++g) { A1[g] = b1; A2[g] = b2; A3[g] = b3; A4[g] = b4; }
#pragma unroll 2
        for (int i = 0; i < 64; ++i) {
            const float w1 = wl[ 4096 + i * 64 + j];
            const float w2 = wl[ 8192 + i * 64 + j];
            const float w3 = wl[12288 + i * 64 + j];
            const float w4 = wl[16384 + i * 64 + j];
#pragma unroll
            for (int g = 0; g < 8; ++g) {
                const float bv = bs[(grp * 8 + g) * 64 + i];
                A1[g] += bv * w1; A2[g] += bv * w2; A3[g] += bv * w3; A4[g] += bv * w4;
            }
        }
#pragma unroll
        for (int g = 0; g < 8; ++g) {
            const size_t o = (size_t)(base + grp * 8 + g) * 64 + j;
            const float t1 = tanhf(A1[g]);
            const float t2 = tanhf(A2[g]);
            const float ta = 1.f / (1.f + expf(-A3[g]));
            const float de = 1.f / (1.f + expf(-A4[g]));
            cand[o]  = t1 * (1.f - ta) + t2 * ta;
            decay[o] = de;
        }
        __syncthreads();   // before next round overwrites xs/bs
    }
}

// ---------------------------------------------------------------------------
// Chunked scan of h_t = d_t*h_{t-1} + (1-d_t)*c_t  over S=2048.
// 64 chunks of 32 steps; chain = (b, p) with p = nh*64+ns (1024 per b).
// ---------------------------------------------------------------------------
__global__ __launch_bounds__(256)
void scan_compose(const float* __restrict__ decay, const float* __restrict__ cand,
                  float* __restrict__ Ach, float* __restrict__ Bch)
{
    const int idx = blockIdx.x * 256 + threadIdx.x;   // 8*64*1024
    const int p  = idx & 1023;
    const int rest = idx >> 10;
    const int ch = rest & 63, b = rest >> 6;
    float A = 1.f, Bv = 0.f;
    const size_t base = ((size_t)(b * SN + ch * 32) << 10) + p;
    for (int t = 0; t < 32; ++t) {
        const float d = decay[base + ((size_t)t << 10)];
        const float c = cand [base + ((size_t)t << 10)];
        A  *= d;
        Bv  = d * Bv + (1.f - d) * c;
    }
    Ach[(ch << 13) + (b << 10) + p] = A;
    Bch[(ch << 13) + (b << 10) + p] = Bv;
}

__global__ __launch_bounds__(256)
void scan_chunks(const float* __restrict__ Ach, const float* __restrict__ Bch,
                 float* __restrict__ hstart)
{
    const int q = blockIdx.x * 256 + threadIdx.x;    // 8192 chains
    float h = 0.f;
    for (int ch = 0; ch < 64; ++ch) {
        hstart[(ch << 13) + q] = h;
        h = Ach[(ch << 13) + q] * h + Bch[(ch << 13) + q];
    }
}

__global__ __launch_bounds__(256)
void scan_apply(const float* __restrict__ decay, float* __restrict__ candh,
                const float* __restrict__ hstart)
{
    const int idx = blockIdx.x * 256 + threadIdx.x;
    const int p  = idx & 1023;
    const int rest = idx >> 10;
    const int ch = rest & 63, b = rest >> 6;
    float h = hstart[(ch << 13) + (b << 10) + p];
    const size_t base = ((size_t)(b * SN + ch * 32) << 10) + p;
    for (int t = 0; t < 32; ++t) {
        const size_t o = base + ((size_t)t << 10);
        const float d = decay[o];
        const float c = candh[o];
        h = d * h + (1.f - d) * c;
        candh[o] = h;      // h_seq overwrites candidate in place
    }
}

// ---------------------------------------------------------------------------
// state_out (64x64 matvec) + bias, then gate with silu(z) (precomputed).
// ---------------------------------------------------------------------------
__global__ __launch_bounds__(256)
void stateout_gate(const float* __restrict__ h, const float* __restrict__ sow,
                   const float* __restrict__ sob, const float* __restrict__ zs,
                   float* __restrict__ gated)
{
    __shared__ float wl[4096];
    __shared__ float hs[32 * 64];
    const int tid = threadIdx.x;
    for (int i = tid; i < 1024; i += 256)
        ((float4*)wl)[i] = ((const float4*)sow)[i];
    __syncthreads();

    const int j = tid & 63, grp = tid >> 6;
    for (int r = 0; r < 4; ++r) {
        const int base = (blockIdx.x * 4 + r) * 32;
        for (int i = tid; i < 512; i += 256)
            ((float4*)hs)[i] = ((const float4*)(h + (size_t)base * 64))[i];
        __syncthreads();

        float a[8];
        const float bj = sob[j];
#pragma unroll
        for (int g = 0; g < 8; ++g) a[g] = bj;
#pragma unroll 4
        for (int i = 0; i < 64; ++i) {
            const float w = wl[i * 64 + j];
#pragma unroll
            for (int g = 0; g < 8; ++g) a[g] += hs[(grp * 8 + g) * 64 + i] * w;
        }
#pragma unroll
        for (int g = 0; g < 8; ++g) {
            const size_t o = (size_t)(base + grp * 8 + g) * 64 + j;
            gated[o] = a[g] * zs[o];
        }
        __syncthreads();
    }
}

// ---------------------------------------------------------------------------
extern "C" void kernel_launch(void* const* d_in, const int* in_sizes, int n_in,
                              void* d_out, int out_size, void* d_ws, size_t ws_size,
                              hipStream_t stream)
{
    const float* x     = (const float*)d_in[0];
    const float* ipw   = (const float*)d_in[1];
    const float* cw    = (const float*)d_in[2];
    const float* cb    = (const float*)d_in[3];
    const float* bbw   = (const float*)d_in[4];
    const float* bbb   = (const float*)d_in[5];
    const float* f1w   = (const float*)d_in[6];
    const float* f1b   = (const float*)d_in[7];
    const float* f2w   = (const float*)d_in[8];
    const float* f2b   = (const float*)d_in[9];
    const float* tauw  = (const float*)d_in[10];
    const float* taub  = (const float*)d_in[11];
    const float* taub2 = (const float*)d_in[12];
    const float* decw  = (const float*)d_in[13];
    const float* decb  = (const float*)d_in[14];
    const float* sow   = (const float*)d_in[15];
    const float* sob   = (const float*)d_in[16];
    const float* opw   = (const float*)d_in[17];

    float* out = (float*)d_out;
    char*  ws  = (char*)d_ws;

    // Workspace map (bytes). One big buffer = NTOK*HN*4 = 67,108,864.
    const size_t BUF = (size_t)NTOK * HN * sizeof(float);
    float* xpath = (float*)(ws);             // K1 out -> dead after conv; reused as decay
    float* xh    = (float*)(ws + BUF);       // conv out -> dead after backbone; reused as gated
    float* cand  = (float*)(ws + 2 * BUF);   // backbone out -> h_seq in place
    float* Ach   = (float*)(ws + 3 * BUF);   // 8192*64 f32 = 2MB
    float* Bch   = Ach + 524288;
    float* hst   = Bch + 524288;
    float* decay = xpath;
    float* gated = xh;
    float* zsilu = out;                      // d_out as scratch until final GEMM

    // 1) in_proj GEMM + split + silu(z)
    sgemm128<2048, 1><<<dim3(16, 128), 256, 0, stream>>>(x, ipw, xpath, zsilu);
    // 2) conv + silu
    conv_silu<<<NTOK * HN / 256, 256, 0, stream>>>(xpath, cw, cb, xh);
    // 3) backbone -> cand, decay
    backbone<<<2048, 256, 0, stream>>>(xh, bbw, bbb, f1w, f1b, f2w, f2b,
                                       tauw, taub, taub2, decw, decb, cand, decay);
    // 4) chunked scan -> h_seq (in cand)
    scan_compose<<<2048, 256, 0, stream>>>(decay, cand, Ach, Bch);
    scan_chunks<<<32, 256, 0, stream>>>(Ach, Bch, hst);
    scan_apply<<<2048, 256, 0, stream>>>(decay, cand, hst);
    // 5) state_out + gate
    stateout_gate<<<2048, 256, 0, stream>>>(cand, sow, sob, zsilu, gated);
    // 6) out_proj GEMM
    sgemm128<1024, 0><<<dim3(8, 128), 256, 0, stream>>>(gated, opw, out, nullptr);
}

// Round 2
// 870.791 us; speedup vs baseline: 1.9875x; 1.9875x over previous
//
#include <hip/hip_runtime.h>
#include <hip/hip_bf16.h>
#include <math.h>

// Problem constants
#define BN   8
#define SN   2048
#define HN   1024
#define NTOK 16384   // B*S
#define NHD  16
#define HDD  64
#define NSD  64

typedef __attribute__((ext_vector_type(8))) short short8;
typedef __attribute__((ext_vector_type(4))) float f32x4;

__device__ __forceinline__ float fsig(float x)  { return 1.f / (1.f + __expf(-x)); }
__device__ __forceinline__ float fsilu(float x) { return x / (1.f + __expf(-x)); }
__device__ __forceinline__ float ftanh(float x) {
    const float t = __expf(-2.f * fabsf(x));
    const float r = (1.f - t) / (1.f + t);
    return x >= 0.f ? r : -r;
}
__device__ __forceinline__ void hilo(float v, __hip_bfloat16& h, __hip_bfloat16& l) {
    h = __float2bfloat16(v);
    l = __float2bfloat16(v - __bfloat162float(h));
}
__device__ __forceinline__ void gload_lds16(const void* g, void* l) {
    __builtin_amdgcn_global_load_lds(
        (const __attribute__((address_space(1))) unsigned int*)g,
        (__attribute__((address_space(3))) unsigned int*)l, 16, 0, 0);
}

// ---------------------------------------------------------------------------
// x (16384x1024 f32) -> A (16384x2048 bf16): [hi | lo] per row
// ---------------------------------------------------------------------------
__global__ __launch_bounds__(256)
void x_to_a(const float* __restrict__ X, __hip_bfloat16* __restrict__ A)
{
    const int idx = blockIdx.x * 256 + threadIdx.x;   // 4M float4s
    const int r  = idx >> 8;
    const int c4 = (idx & 255) * 4;
    const float4 v = *(const float4*)&X[(size_t)r * 1024 + c4];
    union { ushort4 u; __hip_bfloat16 b[4]; } H, L;
    hilo(v.x, H.b[0], L.b[0]);
    hilo(v.y, H.b[1], L.b[1]);
    hilo(v.z, H.b[2], L.b[2]);
    hilo(v.w, H.b[3], L.b[3]);
    *(ushort4*)&A[(size_t)r * 2048 + c4]        = H.u;
    *(ushort4*)&A[(size_t)r * 2048 + 1024 + c4] = L.u;
}

// ---------------------------------------------------------------------------
// W (1024 x N f32, (in,out)) -> BT (N x 2048 bf16): BT[n][k]=hi(W[k][n]),
// BT[n][1024+k]=lo(W[k][n]).  64x64 LDS-tiled transpose.
// ---------------------------------------------------------------------------
__global__ __launch_bounds__(256)
void w_to_bt(const float* __restrict__ W, __hip_bfloat16* __restrict__ BT, int N)
{
    __shared__ float t[64][65];
    const int k0 = blockIdx.x * 64;
    const int n0 = blockIdx.y * 64;
    const int c  = threadIdx.x & 63, r4 = threadIdx.x >> 6;
#pragma unroll
    for (int rr = 0; rr < 64; rr += 4)
        t[rr + r4][c] = W[(size_t)(k0 + rr + r4) * N + n0 + c];
    __syncthreads();
#pragma unroll
    for (int rr = 0; rr < 64; rr += 4) {
        const float v = t[c][rr + r4];
        __hip_bfloat16 h, l;
        hilo(v, h, l);
        const size_t o = (size_t)(n0 + rr + r4) * 2048 + k0 + c;
        BT[o]        = h;
        BT[o + 1024] = l;
    }
}

// ---------------------------------------------------------------------------
// MFMA GEMM: C(16384 x NT*128) = A(16384x1024) * B(1024 x NT*128) in split
// bf16: A stored [16384][2048]=[hi|lo], B stored transposed [NT*128][2048].
// C = Ah*Bh + Ah*Bl + Al*Bh (fp32 accum).  128x128 tile, BK=32, 4 waves,
// 16x16x32 MFMA, global_load_lds(16B) staging, XOR chunk swizzle.
// MODE 0: store C to out0 (stride NT*128).
// MODE 1: cols<1024 -> out0 (stride 1024); cols>=1024 -> silu -> out1.
// ---------------------------------------------------------------------------
template<int NT, int MODE>
__global__ __launch_bounds__(256)
void mfma_gemm(const __hip_bfloat16* __restrict__ A,
               const __hip_bfloat16* __restrict__ BT,
               float* __restrict__ out0, float* __restrict__ out1)
{
    __shared__ __hip_bfloat16 lds[4][4096];   // Ahi, Alo, Bhi, Blo: [128][32] each
    const int tid  = threadIdx.x;
    const int lane = tid & 63, wave = tid >> 6;
    const int wr   = wave >> 1, wc = wave & 1;

    // XCD-aware bijective swizzle (gridDim.x % 8 == 0 for both call sites)
    const int nwg = gridDim.x;
    const int cpx = nwg >> 3;
    const int swz = (blockIdx.x & 7) * cpx + (blockIdx.x >> 3);
    const int mt = swz / NT, nt = swz % NT;
    const int row0 = mt * 128, col0 = nt * 128;

    // staging: each wave stages two 16-row blocks per tile; lane covers
    // LDS row rb*16 + (lane>>2), chunk (lane&3).  Source chunk is
    // pre-swizzled: c = (lane&3) ^ ((row>>1)&3) = (lane&3) ^ ((lane>>3)&3).
    const int srow   = lane >> 2;
    const int schunk = (lane & 3) ^ ((lane >> 3) & 3);

    f32x4 acc[4][4];
#pragma unroll
    for (int m = 0; m < 4; ++m)
#pragma unroll
        for (int n = 0; n < 4; ++n) acc[m][n] = (f32x4)0.f;

    // read-side element offset within a tile row-block (swizzled chunk)
    const int rdbase = (lane & 15) * 32 + (((lane >> 4) ^ ((lane >> 1) & 3)) * 8);

    for (int kk = 0; kk < 1024; kk += 32) {
        __syncthreads();   // previous compute done before overwrite
#pragma unroll
        for (int it = 0; it < 2; ++it) {
            const int rb = wave * 2 + it;
            const int rA = rb * 16 + srow;
            const __hip_bfloat16* ga = &A [(size_t)(row0 + rA) * 2048 + kk + schunk * 8];
            const __hip_bfloat16* gb = &BT[(size_t)(col0 + rA) * 2048 + kk + schunk * 8];
            gload_lds16(ga,        &lds[0][rb * 512]);
            gload_lds16(ga + 1024, &lds[1][rb * 512]);
            gload_lds16(gb,        &lds[2][rb * 512]);
            gload_lds16(gb + 1024, &lds[3][rb * 512]);
        }
        __syncthreads();   // staging drained (compiler emits vmcnt(0))

        short8 ah[4], al[4], bh[4], bl[4];
#pragma unroll
        for (int m = 0; m < 4; ++m) {
            const int off = (wr * 64 + m * 16) * 32 + rdbase;
            ah[m] = *(const short8*)&lds[0][off];
            al[m] = *(const short8*)&lds[1][off];
        }
#pragma unroll
        for (int n = 0; n < 4; ++n) {
            const int off = (wc * 64 + n * 16) * 32 + rdbase;
            bh[n] = *(const short8*)&lds[2][off];
            bl[n] = *(const short8*)&lds[3][off];
        }
#pragma unroll
        for (int m = 0; m < 4; ++m)
#pragma unroll
            for (int n = 0; n < 4; ++n) {
                acc[m][n] = __builtin_amdgcn_mfma_f32_16x16x32_bf16(ah[m], bh[n], acc[m][n], 0, 0, 0);
                acc[m][n] = __builtin_amdgcn_mfma_f32_16x16x32_bf16(ah[m], bl[n], acc[m][n], 0, 0, 0);
                acc[m][n] = __builtin_amdgcn_mfma_f32_16x16x32_bf16(al[m], bh[n], acc[m][n], 0, 0, 0);
            }
    }

    // epilogue: C/D layout col=lane&15, row=(lane>>4)*4+q
    const int orow = (lane >> 4) * 4, ocol = lane & 15;
#pragma unroll
    for (int m = 0; m < 4; ++m)
#pragma unroll
        for (int n = 0; n < 4; ++n) {
            const int c = col0 + wc * 64 + n * 16 + ocol;
#pragma unroll
            for (int q = 0; q < 4; ++q) {
                const int r = row0 + wr * 64 + m * 16 + orow + q;
                const float v = acc[m][n][q];
                if (MODE == 0) {
                    out0[(size_t)r * (NT * 128) + c] = v;
                } else {
                    if (c < 1024) out0[(size_t)r * 1024 + c] = v;
                    else          out1[(size_t)r * 1024 + (c - 1024)] = fsilu(v);
                }
            }
        }
}

// ---------------------------------------------------------------------------
// Depthwise causal conv (K=4) + bias + silu.
// ---------------------------------------------------------------------------
__global__ __launch_bounds__(256)
void conv_silu(const float* __restrict__ xp, const float* __restrict__ cw,
               const float* __restrict__ cb, float* __restrict__ xh)
{
    const int idx = blockIdx.x * 256 + threadIdx.x;
    const int c  = idx & 1023;
    const int bt = idx >> 10;
    const int t  = bt & (SN - 1);
    float acc = cb[c];
#pragma unroll
    for (int k = 0; k < 4; ++k) {
        const int tt = t - 3 + k;
        if (tt >= 0)
            acc += cw[c * 4 + k] * xp[((size_t)(bt - 3 + k) << 10) + c];
    }
    xh[(size_t)idx] = fsilu(acc);
}

// ---------------------------------------------------------------------------
// Backbone (5x 64x64 matvecs per token-head, weights in LDS).
// ---------------------------------------------------------------------------
__global__ __launch_bounds__(256)
void backbone(const float* __restrict__ xh,
              const float* __restrict__ bbw, const float* __restrict__ bbb,
              const float* __restrict__ f1w, const float* __restrict__ f1b,
              const float* __restrict__ f2w, const float* __restrict__ f2b,
              const float* __restrict__ tauw, const float* __restrict__ taub,
              const float* __restrict__ taub2,
              const float* __restrict__ decw, const float* __restrict__ decb,
              float* __restrict__ cand, float* __restrict__ decay)
{
    __shared__ float wl[5 * 4096];
    __shared__ float xs[32 * 64];
    __shared__ float bs[32 * 64];
    const int tid = threadIdx.x;

    for (int i = tid; i < 1024; i += 256) {
        ((float4*)(wl        ))[i] = ((const float4*)bbw )[i];
        ((float4*)(wl +  4096))[i] = ((const float4*)f1w )[i];
        ((float4*)(wl +  8192))[i] = ((const float4*)f2w )[i];
        ((float4*)(wl + 12288))[i] = ((const float4*)tauw)[i];
        ((float4*)(wl + 16384))[i] = ((const float4*)decw)[i];
    }
    __syncthreads();

    const int j = tid & 63, grp = tid >> 6;

    for (int r = 0; r < 4; ++r) {
        const int base = (blockIdx.x * 4 + r) * 32;
        for (int i = tid; i < 512; i += 256)
            ((float4*)xs)[i] = ((const float4*)(xh + (size_t)base * 64))[i];
        __syncthreads();

        float a0[8];
#pragma unroll
        for (int g = 0; g < 8; ++g) a0[g] = bbb[j];
#pragma unroll 4
        for (int i = 0; i < 64; ++i) {
            const float w = wl[i * 64 + j];
#pragma unroll
            for (int g = 0; g < 8; ++g) a0[g] += xs[(grp * 8 + g) * 64 + i] * w;
        }
#pragma unroll
        for (int g = 0; g < 8; ++g)
            bs[(grp * 8 + g) * 64 + j] = fsilu(a0[g]);
        __syncthreads();

        float A1[8], A2[8], A3[8], A4[8];
        const float b1 = f1b[j], b2 = f2b[j], b3 = taub[j] + taub2[j], b4 = decb[j];
#pragma unroll
        for (int g = 0; g < 8; ++g) { A1[g] = b1; A2[g] = b2; A3[g] = b3; A4[g] = b4; }
#pragma unroll 2
        for (int i = 0; i < 64; ++i) {
            const float w1 = wl[ 4096 + i * 64 + j];
            const float w2 = wl[ 8192 + i * 64 + j];
            const float w3 = wl[12288 + i * 64 + j];
            const float w4 = wl[16384 + i * 64 + j];
#pragma unroll
            for (int g = 0; g < 8; ++g) {
                const float bv = bs[(grp * 8 + g) * 64 + i];
                A1[g] += bv * w1; A2[g] += bv * w2; A3[g] += bv * w3; A4[g] += bv * w4;
            }
        }
#pragma unroll
        for (int g = 0; g < 8; ++g) {
            const size_t o = (size_t)(base + grp * 8 + g) * 64 + j;
            const float t1 = ftanh(A1[g]);
            const float t2 = ftanh(A2[g]);
            const float ta = fsig(A3[g]);
            cand[o]  = t1 * (1.f - ta) + t2 * ta;
            decay[o] = fsig(A4[g]);
        }
        __syncthreads();
    }
}

// ---------------------------------------------------------------------------
// Chunked scan: h_t = d*h + (1-d)*c over S=2048 (64 chunks x 32).
// ---------------------------------------------------------------------------
__global__ __launch_bounds__(256)
void scan_compose(const float* __restrict__ decay, const float* __restrict__ cand,
                  float* __restrict__ Ach, float* __restrict__ Bch)
{
    const int idx = blockIdx.x * 256 + threadIdx.x;
    const int p  = idx & 1023;
    const int rest = idx >> 10;
    const int ch = rest & 63, b = rest >> 6;
    float A = 1.f, Bv = 0.f;
    const size_t base = ((size_t)(b * SN + ch * 32) << 10) + p;
    for (int t = 0; t < 32; ++t) {
        const float d = decay[base + ((size_t)t << 10)];
        const float c = cand [base + ((size_t)t << 10)];
        A  *= d;
        Bv  = d * Bv + (1.f - d) * c;
    }
    Ach[(ch << 13) + (b << 10) + p] = A;
    Bch[(ch << 13) + (b << 10) + p] = Bv;
}

__global__ __launch_bounds__(256)
void scan_chunks(const float* __restrict__ Ach, const float* __restrict__ Bch,
                 float* __restrict__ hstart)
{
    const int q = blockIdx.x * 256 + threadIdx.x;
    float h = 0.f;
    for (int ch = 0; ch < 64; ++ch) {
        hstart[(ch << 13) + q] = h;
        h = Ach[(ch << 13) + q] * h + Bch[(ch << 13) + q];
    }
}

__global__ __launch_bounds__(256)
void scan_apply(const float* __restrict__ decay, float* __restrict__ candh,
                const float* __restrict__ hstart)
{
    const int idx = blockIdx.x * 256 + threadIdx.x;
    const int p  = idx & 1023;
    const int rest = idx >> 10;
    const int ch = rest & 63, b = rest >> 6;
    float h = hstart[(ch << 13) + (b << 10) + p];
    const size_t base = ((size_t)(b * SN + ch * 32) << 10) + p;
    for (int t = 0; t < 32; ++t) {
        const size_t o = base + ((size_t)t << 10);
        const float d = decay[o];
        const float c = candh[o];
        h = d * h + (1.f - d) * c;
        candh[o] = h;
    }
}

// ---------------------------------------------------------------------------
// state_out matvec + bias, gate with silu(z), emit bf16 hi|lo for out_proj.
// ---------------------------------------------------------------------------
__global__ __launch_bounds__(256)
void stateout_gate(const float* __restrict__ h, const float* __restrict__ sow,
                   const float* __restrict__ sob, const float* __restrict__ zs,
                   __hip_bfloat16* __restrict__ gA)
{
    __shared__ float wl[4096];
    __shared__ float hs[32 * 64];
    const int tid = threadIdx.x;
    for (int i = tid; i < 1024; i += 256)
        ((float4*)wl)[i] = ((const float4*)sow)[i];
    __syncthreads();

    const int j = tid & 63, grp = tid >> 6;
    for (int r = 0; r < 4; ++r) {
        const int base = (blockIdx.x * 4 + r) * 32;
        for (int i = tid; i < 512; i += 256)
            ((float4*)hs)[i] = ((const float4*)(h + (size_t)base * 64))[i];
        __syncthreads();

        float a[8];
        const float bj = sob[j];
#pragma unroll
        for (int g = 0; g < 8; ++g) a[g] = bj;
#pragma unroll 4
        for (int i = 0; i < 64; ++i) {
            const float w = wl[i * 64 + j];
#pragma unroll
            for (int g = 0; g < 8; ++g) a[g] += hs[(grp * 8 + g) * 64 + i] * w;
        }
#pragma unroll
        for (int g = 0; g < 8; ++g) {
            const size_t o = (size_t)(base + grp * 8 + g) * 64 + j;
            const float v = a[g] * zs[o];
            const size_t row = o >> 10, col = o & 1023;
            __hip_bfloat16 hb, lb;
            hilo(v, hb, lb);
            gA[row * 2048 + col]        = hb;
            gA[row * 2048 + 1024 + col] = lb;
        }
        __syncthreads();
    }
}

// ---------------------------------------------------------------------------
extern "C" void kernel_launch(void* const* d_in, const int* in_sizes, int n_in,
                              void* d_out, int out_size, void* d_ws, size_t ws_size,
                              hipStream_t stream)
{
    const float* x     = (const float*)d_in[0];
    const float* ipw   = (const float*)d_in[1];
    const float* cw    = (const float*)d_in[2];
    const float* cb    = (const float*)d_in[3];
    const float* bbw   = (const float*)d_in[4];
    const float* bbb   = (const float*)d_in[5];
    const float* f1w   = (const float*)d_in[6];
    const float* f1b   = (const float*)d_in[7];
    const float* f2w   = (const float*)d_in[8];
    const float* f2b   = (const float*)d_in[9];
    const float* tauw  = (const float*)d_in[10];
    const float* taub  = (const float*)d_in[11];
    const float* taub2 = (const float*)d_in[12];
    const float* decw  = (const float*)d_in[13];
    const float* decb  = (const float*)d_in[14];
    const float* sow   = (const float*)d_in[15];
    const float* sob   = (const float*)d_in[16];
    const float* opw   = (const float*)d_in[17];

    float* out = (float*)d_out;
    char*  ws  = (char*)d_ws;
    const size_t MB = 1024 * 1024;

    // Workspace map (198 MiB total):
    //  @0Mi   (64Mi): Ahl (bf16)  -> xh (f32)  -> gA (bf16)
    //  @64Mi  (64Mi): xpath (f32) -> decay (f32)
    //  @128Mi (64Mi): BTin (8Mi, dead before cand) -> cand/h (f32)
    //  @192Mi (6Mi) : Ach|Bch|hst -> BTout (4Mi)
    __hip_bfloat16* Ahl   = (__hip_bfloat16*)(ws);
    float*          xpath = (float*)(ws + 64 * MB);
    __hip_bfloat16* BTin  = (__hip_bfloat16*)(ws + 128 * MB);
    float*          cand  = (float*)(ws + 128 * MB);
    float*          Ach   = (float*)(ws + 192 * MB);
    float*          Bch   = Ach + 524288;
    float*          hst   = Bch + 524288;
    __hip_bfloat16* BTout = (__hip_bfloat16*)(ws + 192 * MB);
    float*          xh    = (float*)(ws);
    __hip_bfloat16* gA    = (__hip_bfloat16*)(ws);
    float*          decay = xpath;
    float*          zsilu = out;   // d_out as scratch until final GEMM

    // 1) hi/lo conversions for in_proj
    x_to_a<<<16384, 256, 0, stream>>>(x, Ahl);
    w_to_bt<<<dim3(16, 32), 256, 0, stream>>>(ipw, BTin, 2048);
    // 2) in_proj GEMM (split-bf16 MFMA) + silu(z)
    mfma_gemm<16, 1><<<2048, 256, 0, stream>>>(Ahl, BTin, xpath, zsilu);
    // 3) conv + silu
    conv_silu<<<65536, 256, 0, stream>>>(xpath, cw, cb, xh);
    // 4) backbone -> cand, decay
    backbone<<<2048, 256, 0, stream>>>(xh, bbw, bbb, f1w, f1b, f2w, f2b,
                                       tauw, taub, taub2, decw, decb, cand, decay);
    // 5) chunked scan -> h (in cand)
    scan_compose<<<2048, 256, 0, stream>>>(decay, cand, Ach, Bch);
    scan_chunks<<<32, 256, 0, stream>>>(Ach, Bch, hst);
    scan_apply<<<2048, 256, 0, stream>>>(decay, cand, hst);
    // 6) out_proj weight conversion (scan scratch now dead)
    w_to_bt<<<dim3(16, 16), 256, 0, stream>>>(opw, BTout, 1024);
    // 7) state_out + gate -> bf16 hi|lo
    stateout_gate<<<2048, 256, 0, stream>>>(cand, sow, sob, zsilu, gA);
    // 8) out_proj GEMM
    mfma_gemm<8, 0><<<1024, 256, 0, stream>>>(gA, BTout, out, nullptr);
}

// Round 3
// 617.477 us; speedup vs baseline: 2.8028x; 1.4102x over previous
//
#include <hip/hip_runtime.h>
#include <hip/hip_bf16.h>
#include <math.h>

// Problem constants
#define BN   8
#define SN   2048
#define HN   1024
#define NTOK 16384   // B*S
#define NHD  16
#define HDD  64
#define NSD  64

typedef __attribute__((ext_vector_type(8))) short short8;
typedef __attribute__((ext_vector_type(4))) float f32x4;

__device__ __forceinline__ float fsig(float x)  { return 1.f / (1.f + __expf(-x)); }
__device__ __forceinline__ float fsilu(float x) { return x / (1.f + __expf(-x)); }
__device__ __forceinline__ float ftanh(float x) {
    const float t = __expf(-2.f * fabsf(x));
    const float r = (1.f - t) / (1.f + t);
    return x >= 0.f ? r : -r;
}
__device__ __forceinline__ void hilo(float v, __hip_bfloat16& h, __hip_bfloat16& l) {
    h = __float2bfloat16(v);
    l = __float2bfloat16(v - __bfloat162float(h));
}
__device__ __forceinline__ void gload_lds16(const void* g, void* l) {
    __builtin_amdgcn_global_load_lds(
        (const __attribute__((address_space(1))) unsigned int*)g,
        (__attribute__((address_space(3))) unsigned int*)l, 16, 0, 0);
}

// ---------------------------------------------------------------------------
// x (16384x1024 f32) -> A (16384x2048 bf16): [hi | lo] per row
// ---------------------------------------------------------------------------
__global__ __launch_bounds__(256)
void x_to_a(const float* __restrict__ X, __hip_bfloat16* __restrict__ A)
{
    const int idx = blockIdx.x * 256 + threadIdx.x;   // 4M float4s
    const int r  = idx >> 8;
    const int c4 = (idx & 255) * 4;
    const float4 v = *(const float4*)&X[(size_t)r * 1024 + c4];
    union { ushort4 u; __hip_bfloat16 b[4]; } H, L;
    hilo(v.x, H.b[0], L.b[0]);
    hilo(v.y, H.b[1], L.b[1]);
    hilo(v.z, H.b[2], L.b[2]);
    hilo(v.w, H.b[3], L.b[3]);
    *(ushort4*)&A[(size_t)r * 2048 + c4]        = H.u;
    *(ushort4*)&A[(size_t)r * 2048 + 1024 + c4] = L.u;
}

// ---------------------------------------------------------------------------
// W (1024 x N f32, (in,out)) -> BT (N x 2048 bf16): BT[n][k]=hi(W[k][n]),
// BT[n][1024+k]=lo(W[k][n]).  64x64 LDS-tiled transpose.
// ---------------------------------------------------------------------------
__global__ __launch_bounds__(256)
void w_to_bt(const float* __restrict__ W, __hip_bfloat16* __restrict__ BT, int N)
{
    __shared__ float t[64][65];
    const int k0 = blockIdx.x * 64;
    const int n0 = blockIdx.y * 64;
    const int c  = threadIdx.x & 63, r4 = threadIdx.x >> 6;
#pragma unroll
    for (int rr = 0; rr < 64; rr += 4)
        t[rr + r4][c] = W[(size_t)(k0 + rr + r4) * N + n0 + c];
    __syncthreads();
#pragma unroll
    for (int rr = 0; rr < 64; rr += 4) {
        const float v = t[c][rr + r4];
        __hip_bfloat16 h, l;
        hilo(v, h, l);
        const size_t o = (size_t)(n0 + rr + r4) * 2048 + k0 + c;
        BT[o]        = h;
        BT[o + 1024] = l;
    }
}

// ---------------------------------------------------------------------------
// 5 backbone weight mats (64x64 f32, (k,n)) -> WT5[mat][n][16 chunks x 8 bf16]
// hi octet o at chunk (o ^ (n&15)), lo at ((o|8) ^ (n&15)).  (pre-swizzled)
// ---------------------------------------------------------------------------
__global__ __launch_bounds__(256)
void w5_to_wt(const float* __restrict__ w0, const float* __restrict__ w1,
              const float* __restrict__ w2, const float* __restrict__ w3,
              const float* __restrict__ w4, __hip_bfloat16* __restrict__ WT5)
{
    const int idx = blockIdx.x * 256 + threadIdx.x;
    if (idx >= 2560) return;
    const int o = idx & 7, n = (idx >> 3) & 63, mat = idx >> 9;
    const float* W = mat == 0 ? w0 : mat == 1 ? w1 : mat == 2 ? w2 : mat == 3 ? w3 : w4;
    alignas(16) __hip_bfloat16 hb[8], lb[8];
#pragma unroll
    for (int j = 0; j < 8; ++j) {
        const float v = W[(o * 8 + j) * 64 + n];
        hilo(v, hb[j], lb[j]);
    }
    __hip_bfloat16* row = WT5 + (size_t)(mat * 64 + n) * 128;
    *(short8*)&row[((o     ) ^ (n & 15)) * 8] = *(const short8*)hb;
    *(short8*)&row[((o | 8) ^ (n & 15)) * 8] = *(const short8*)lb;
}

// ---------------------------------------------------------------------------
// MFMA GEMM (split bf16, 3 products).  Unchanged from round 2.
// ---------------------------------------------------------------------------
template<int NT, int MODE>
__global__ __launch_bounds__(256)
void mfma_gemm(const __hip_bfloat16* __restrict__ A,
               const __hip_bfloat16* __restrict__ BT,
               float* __restrict__ out0, float* __restrict__ out1)
{
    __shared__ __hip_bfloat16 lds[4][4096];   // Ahi, Alo, Bhi, Blo: [128][32] each
    const int tid  = threadIdx.x;
    const int lane = tid & 63, wave = tid >> 6;
    const int wr   = wave >> 1, wc = wave & 1;

    const int nwg = gridDim.x;
    const int cpx = nwg >> 3;
    const int swz = (blockIdx.x & 7) * cpx + (blockIdx.x >> 3);
    const int mt = swz / NT, nt = swz % NT;
    const int row0 = mt * 128, col0 = nt * 128;

    const int srow   = lane >> 2;
    const int schunk = (lane & 3) ^ ((lane >> 3) & 3);

    f32x4 acc[4][4];
#pragma unroll
    for (int m = 0; m < 4; ++m)
#pragma unroll
        for (int n = 0; n < 4; ++n) acc[m][n] = (f32x4)0.f;

    const int rdbase = (lane & 15) * 32 + (((lane >> 4) ^ ((lane >> 1) & 3)) * 8);

    for (int kk = 0; kk < 1024; kk += 32) {
        __syncthreads();
#pragma unroll
        for (int it = 0; it < 2; ++it) {
            const int rb = wave * 2 + it;
            const int rA = rb * 16 + srow;
            const __hip_bfloat16* ga = &A [(size_t)(row0 + rA) * 2048 + kk + schunk * 8];
            const __hip_bfloat16* gb = &BT[(size_t)(col0 + rA) * 2048 + kk + schunk * 8];
            gload_lds16(ga,        &lds[0][rb * 512]);
            gload_lds16(ga + 1024, &lds[1][rb * 512]);
            gload_lds16(gb,        &lds[2][rb * 512]);
            gload_lds16(gb + 1024, &lds[3][rb * 512]);
        }
        __syncthreads();

        short8 ah[4], al[4], bh[4], bl[4];
#pragma unroll
        for (int m = 0; m < 4; ++m) {
            const int off = (wr * 64 + m * 16) * 32 + rdbase;
            ah[m] = *(const short8*)&lds[0][off];
            al[m] = *(const short8*)&lds[1][off];
        }
#pragma unroll
        for (int n = 0; n < 4; ++n) {
            const int off = (wc * 64 + n * 16) * 32 + rdbase;
            bh[n] = *(const short8*)&lds[2][off];
            bl[n] = *(const short8*)&lds[3][off];
        }
#pragma unroll
        for (int m = 0; m < 4; ++m)
#pragma unroll
            for (int n = 0; n < 4; ++n) {
                acc[m][n] = __builtin_amdgcn_mfma_f32_16x16x32_bf16(ah[m], bh[n], acc[m][n], 0, 0, 0);
                acc[m][n] = __builtin_amdgcn_mfma_f32_16x16x32_bf16(ah[m], bl[n], acc[m][n], 0, 0, 0);
                acc[m][n] = __builtin_amdgcn_mfma_f32_16x16x32_bf16(al[m], bh[n], acc[m][n], 0, 0, 0);
            }
    }

    const int orow = (lane >> 4) * 4, ocol = lane & 15;
#pragma unroll
    for (int m = 0; m < 4; ++m)
#pragma unroll
        for (int n = 0; n < 4; ++n) {
            const int c = col0 + wc * 64 + n * 16 + ocol;
#pragma unroll
            for (int q = 0; q < 4; ++q) {
                const int r = row0 + wr * 64 + m * 16 + orow + q;
                const float v = acc[m][n][q];
                if (MODE == 0) {
                    out0[(size_t)r * (NT * 128) + c] = v;
                } else {
                    if (c < 1024) out0[(size_t)r * 1024 + c] = v;
                    else          out1[(size_t)r * 1024 + (c - 1024)] = fsilu(v);
                }
            }
        }
}

// ---------------------------------------------------------------------------
// Depthwise causal conv (K=4) + bias + silu -> X as swizzled bf16 hi|lo rows.
// Output row R = bt*16+head (256 B): 16 chunks of 8 bf16; hi octet o at chunk
// (o ^ head), lo at ((o|8) ^ head)  [R&15 == head].
// ---------------------------------------------------------------------------
__global__ __launch_bounds__(256)
void conv_silu_bf(const float* __restrict__ xp, const float* __restrict__ cw,
                  const float* __restrict__ cb, __hip_bfloat16* __restrict__ Xhl)
{
    const int idx = blockIdx.x * 256 + threadIdx.x;   // NTOK*128 octets
    const int g  = idx & 127;
    const int bt = idx >> 7;
    const int t  = bt & (SN - 1);
    const int c0 = g * 8;

    float acc[8];
#pragma unroll
    for (int j = 0; j < 8; ++j) acc[j] = cb[c0 + j];
    float4 cwv[8];
#pragma unroll
    for (int j = 0; j < 8; ++j) cwv[j] = *(const float4*)&cw[(c0 + j) * 4];
    const float* cwf = (const float*)cwv;

#pragma unroll
    for (int k = 0; k < 4; ++k) {
        const int tt = t - 3 + k;
        if (tt >= 0) {
            const float* xr = xp + (((size_t)(bt - 3 + k)) << 10) + c0;
            const float4 u0 = *(const float4*)&xr[0];
            const float4 u1 = *(const float4*)&xr[4];
            const float u[8] = {u0.x, u0.y, u0.z, u0.w, u1.x, u1.y, u1.z, u1.w};
#pragma unroll
            for (int j = 0; j < 8; ++j) acc[j] += cwf[j * 4 + k] * u[j];
        }
    }

    alignas(16) __hip_bfloat16 hb[8], lb[8];
#pragma unroll
    for (int j = 0; j < 8; ++j)
        hilo(fsilu(acc[j]), hb[j], lb[j]);

    const int head = c0 >> 6;
    const int o    = (c0 >> 3) & 7;
    __hip_bfloat16* row = Xhl + ((size_t)bt * 16 + head) * 128;
    *(short8*)&row[((o     ) ^ head) * 8] = *(const short8*)hb;
    *(short8*)&row[((o | 8) ^ head) * 8] = *(const short8*)lb;
}

// ---------------------------------------------------------------------------
// Fused MFMA backbone.  128 token-head rows / block, 4 waves (32 rows each).
// Stage1: bb = silu(X@W0 + bbb) -> LDS (bf16 hi|lo, swizzled).
// Stage2: f1,f2,tau,dec = bb@W[1..4] -> nonlinearities -> cand, decay (f32).
// All LDS tiles use chunk^=row&15 swizzle; global layouts are pre-swizzled so
// global_load_lds copies rows verbatim (linear dest).
// ---------------------------------------------------------------------------
__global__ __launch_bounds__(256, 1)
void backbone_mfma(const __hip_bfloat16* __restrict__ Xhl,
                   const __hip_bfloat16* __restrict__ WT5,
                   const float* __restrict__ bbb,
                   const float* __restrict__ f1b, const float* __restrict__ f2b,
                   const float* __restrict__ taub, const float* __restrict__ taub2,
                   const float* __restrict__ decb,
                   float* __restrict__ cand, float* __restrict__ decay)
{
    __shared__ __hip_bfloat16 Wl[5 * 64 * 128];   // 80 KB
    __shared__ __hip_bfloat16 Xl[128 * 128];      // 32 KB
    __shared__ __hip_bfloat16 Bb[128 * 128];      // 32 KB
    const int tid  = threadIdx.x;
    const int lane = tid & 63, wave = tid >> 6;
    const int l15  = lane & 15, l4 = lane >> 4;

    // stage weights: 5120 16B-chunks (20 rounds x 4 waves x 64 lanes)
#pragma unroll
    for (int r = 0; r < 20; ++r) {
        const int blk = r * 4 + wave;
        gload_lds16(WT5 + blk * 512 + lane * 8, Wl + blk * 512);
    }
    // stage X tile: 2048 chunks (8 rounds)
    const __hip_bfloat16* xsrc = Xhl + (size_t)blockIdx.x * 16384;
#pragma unroll
    for (int r = 0; r < 8; ++r) {
        const int blk = r * 4 + wave;
        gload_lds16(xsrc + blk * 512 + lane * 8, Xl + blk * 512);
    }
    __syncthreads();

    // ---- stage 1 ----
    short8 xa[2][2][2];   // [mt2][kstep][hi/lo]
#pragma unroll
    for (int mt2 = 0; mt2 < 2; ++mt2)
#pragma unroll
        for (int s = 0; s < 2; ++s)
#pragma unroll
            for (int p = 0; p < 2; ++p) {
                const int ch = ((s * 4 + l4) | (p << 3)) ^ l15;
                xa[mt2][s][p] = *(const short8*)&Xl[(wave * 32 + mt2 * 16 + l15) * 128 + ch * 8];
            }

#pragma unroll
    for (int nt = 0; nt < 4; ++nt) {
        short8 wb[2][2];
#pragma unroll
        for (int s = 0; s < 2; ++s)
#pragma unroll
            for (int p = 0; p < 2; ++p) {
                const int ch = ((s * 4 + l4) | (p << 3)) ^ l15;
                wb[s][p] = *(const short8*)&Wl[(nt * 16 + l15) * 128 + ch * 8];
            }
        f32x4 ac[2] = {(f32x4)0.f, (f32x4)0.f};
#pragma unroll
        for (int mt2 = 0; mt2 < 2; ++mt2)
#pragma unroll
            for (int s = 0; s < 2; ++s) {
                ac[mt2] = __builtin_amdgcn_mfma_f32_16x16x32_bf16(xa[mt2][s][0], wb[s][0], ac[mt2], 0, 0, 0);
                ac[mt2] = __builtin_amdgcn_mfma_f32_16x16x32_bf16(xa[mt2][s][0], wb[s][1], ac[mt2], 0, 0, 0);
                ac[mt2] = __builtin_amdgcn_mfma_f32_16x16x32_bf16(xa[mt2][s][1], wb[s][0], ac[mt2], 0, 0, 0);
            }
        const int col = nt * 16 + l15;
        const float bc = bbb[col];
#pragma unroll
        for (int mt2 = 0; mt2 < 2; ++mt2)
#pragma unroll
            for (int q = 0; q < 4; ++q) {
                const int r15 = l4 * 4 + q;
                const int lr  = wave * 32 + mt2 * 16 + r15;
                const float v = fsilu(ac[mt2][q] + bc);
                __hip_bfloat16 h, l;
                hilo(v, h, l);
                Bb[lr * 128 + (((col >> 3)     ) ^ r15) * 8 + (col & 7)] = h;
                Bb[lr * 128 + (((col >> 3) | 8) ^ r15) * 8 + (col & 7)] = l;
            }
    }
    __syncthreads();

    // ---- stage 2 ----
    short8 ba[2][2][2];
#pragma unroll
    for (int mt2 = 0; mt2 < 2; ++mt2)
#pragma unroll
        for (int s = 0; s < 2; ++s)
#pragma unroll
            for (int p = 0; p < 2; ++p) {
                const int ch = ((s * 4 + l4) | (p << 3)) ^ l15;
                ba[mt2][s][p] = *(const short8*)&Bb[(wave * 32 + mt2 * 16 + l15) * 128 + ch * 8];
            }

#pragma unroll
    for (int nt = 0; nt < 4; ++nt) {
        f32x4 a2[4][2];
#pragma unroll
        for (int m = 0; m < 4; ++m)
#pragma unroll
            for (int mt2 = 0; mt2 < 2; ++mt2) a2[m][mt2] = (f32x4)0.f;

#pragma unroll
        for (int mat = 0; mat < 4; ++mat) {
            short8 w2[2][2];
#pragma unroll
            for (int s = 0; s < 2; ++s)
#pragma unroll
                for (int p = 0; p < 2; ++p) {
                    const int ch = ((s * 4 + l4) | (p << 3)) ^ l15;
                    w2[s][p] = *(const short8*)&Wl[((mat + 1) * 64 + nt * 16 + l15) * 128 + ch * 8];
                }
#pragma unroll
            for (int mt2 = 0; mt2 < 2; ++mt2)
#pragma unroll
                for (int s = 0; s < 2; ++s) {
                    a2[mat][mt2] = __builtin_amdgcn_mfma_f32_16x16x32_bf16(ba[mt2][s][0], w2[s][0], a2[mat][mt2], 0, 0, 0);
                    a2[mat][mt2] = __builtin_amdgcn_mfma_f32_16x16x32_bf16(ba[mt2][s][0], w2[s][1], a2[mat][mt2], 0, 0, 0);
                    a2[mat][mt2] = __builtin_amdgcn_mfma_f32_16x16x32_bf16(ba[mt2][s][1], w2[s][0], a2[mat][mt2], 0, 0, 0);
                }
        }

        const int col = nt * 16 + l15;
        const float b1 = f1b[col], b2 = f2b[col];
        const float b3 = taub[col] + taub2[col], b4 = decb[col];
        const size_t Rbase = (size_t)blockIdx.x * 128 + wave * 32;
#pragma unroll
        for (int mt2 = 0; mt2 < 2; ++mt2)
#pragma unroll
            for (int q = 0; q < 4; ++q) {
                const size_t R = Rbase + mt2 * 16 + l4 * 4 + q;
                const float f1v = ftanh(a2[0][mt2][q] + b1);
                const float f2v = ftanh(a2[1][mt2][q] + b2);
                const float tv  = fsig (a2[2][mt2][q] + b3);
                const float dv  = fsig (a2[3][mt2][q] + b4);
                cand [R * 64 + col] = f1v * (1.f - tv) + f2v * tv;
                decay[R * 64 + col] = dv;
            }
    }
}

// ---------------------------------------------------------------------------
// Chunked scan: h_t = d*h + (1-d)*c over S=2048 (64 chunks x 32).
// ---------------------------------------------------------------------------
__global__ __launch_bounds__(256)
void scan_compose(const float* __restrict__ decay, const float* __restrict__ cand,
                  float* __restrict__ Ach, float* __restrict__ Bch)
{
    const int idx = blockIdx.x * 256 + threadIdx.x;
    const int p  = idx & 1023;
    const int rest = idx >> 10;
    const int ch = rest & 63, b = rest >> 6;
    float A = 1.f, Bv = 0.f;
    const size_t base = ((size_t)(b * SN + ch * 32) << 10) + p;
    for (int t = 0; t < 32; ++t) {
        const float d = decay[base + ((size_t)t << 10)];
        const float c = cand [base + ((size_t)t << 10)];
        A  *= d;
        Bv  = d * Bv + (1.f - d) * c;
    }
    Ach[(ch << 13) + (b << 10) + p] = A;
    Bch[(ch << 13) + (b << 10) + p] = Bv;
}

__global__ __launch_bounds__(256)
void scan_chunks(const float* __restrict__ Ach, const float* __restrict__ Bch,
                 float* __restrict__ hstart)
{
    const int q = blockIdx.x * 256 + threadIdx.x;
    float h = 0.f;
    for (int ch = 0; ch < 64; ++ch) {
        hstart[(ch << 13) + q] = h;
        h = Ach[(ch << 13) + q] * h + Bch[(ch << 13) + q];
    }
}

__global__ __launch_bounds__(256)
void scan_apply(const float* __restrict__ decay, float* __restrict__ candh,
                const float* __restrict__ hstart)
{
    const int idx = blockIdx.x * 256 + threadIdx.x;
    const int p  = idx & 1023;
    const int rest = idx >> 10;
    const int ch = rest & 63, b = rest >> 6;
    float h = hstart[(ch << 13) + (b << 10) + p];
    const size_t base = ((size_t)(b * SN + ch * 32) << 10) + p;
    for (int t = 0; t < 32; ++t) {
        const size_t o = base + ((size_t)t << 10);
        const float d = decay[o];
        const float c = candh[o];
        h = d * h + (1.f - d) * c;
        candh[o] = h;
    }
}

// ---------------------------------------------------------------------------
// state_out matvec + bias, gate with silu(z), emit bf16 hi|lo for out_proj.
// ---------------------------------------------------------------------------
__global__ __launch_bounds__(256)
void stateout_gate(const float* __restrict__ h, const float* __restrict__ sow,
                   const float* __restrict__ sob, const float* __restrict__ zs,
                   __hip_bfloat16* __restrict__ gA)
{
    __shared__ float wl[4096];
    __shared__ float hs[32 * 64];
    const int tid = threadIdx.x;
    for (int i = tid; i < 1024; i += 256)
        ((float4*)wl)[i] = ((const float4*)sow)[i];
    __syncthreads();

    const int j = tid & 63, grp = tid >> 6;
    for (int r = 0; r < 4; ++r) {
        const int base = (blockIdx.x * 4 + r) * 32;
        for (int i = tid; i < 512; i += 256)
            ((float4*)hs)[i] = ((const float4*)(h + (size_t)base * 64))[i];
        __syncthreads();

        float a[8];
        const float bj = sob[j];
#pragma unroll
        for (int g = 0; g < 8; ++g) a[g] = bj;
#pragma unroll 4
        for (int i = 0; i < 64; ++i) {
            const float w = wl[i * 64 + j];
#pragma unroll
            for (int g = 0; g < 8; ++g) a[g] += hs[(grp * 8 + g) * 64 + i] * w;
        }
#pragma unroll
        for (int g = 0; g < 8; ++g) {
            const size_t o = (size_t)(base + grp * 8 + g) * 64 + j;
            const float v = a[g] * zs[o];
            const size_t row = o >> 10, col = o & 1023;
            __hip_bfloat16 hb, lb;
            hilo(v, hb, lb);
            gA[row * 2048 + col]        = hb;
            gA[row * 2048 + 1024 + col] = lb;
        }
        __syncthreads();
    }
}

// ---------------------------------------------------------------------------
extern "C" void kernel_launch(void* const* d_in, const int* in_sizes, int n_in,
                              void* d_out, int out_size, void* d_ws, size_t ws_size,
                              hipStream_t stream)
{
    const float* x     = (const float*)d_in[0];
    const float* ipw   = (const float*)d_in[1];
    const float* cw    = (const float*)d_in[2];
    const float* cb    = (const float*)d_in[3];
    const float* bbw   = (const float*)d_in[4];
    const float* bbb   = (const float*)d_in[5];
    const float* f1w   = (const float*)d_in[6];
    const float* f1b   = (const float*)d_in[7];
    const float* f2w   = (const float*)d_in[8];
    const float* f2b   = (const float*)d_in[9];
    const float* tauw  = (const float*)d_in[10];
    const float* taub  = (const float*)d_in[11];
    const float* taub2 = (const float*)d_in[12];
    const float* decw  = (const float*)d_in[13];
    const float* decb  = (const float*)d_in[14];
    const float* sow   = (const float*)d_in[15];
    const float* sob   = (const float*)d_in[16];
    const float* opw   = (const float*)d_in[17];

    float* out = (float*)d_out;
    char*  ws  = (char*)d_ws;
    const size_t MB = 1024 * 1024;

    // Workspace map (198 MiB):
    //  @0Mi   (64Mi): Ahl (bf16) -> Xhl (bf16, conv out) -> gA (bf16)
    //  @64Mi  (64Mi): xpath (f32) -> decay (f32)
    //  @128Mi (64Mi): BTin (8Mi, dead before cand) -> cand/h (f32)
    //  @192Mi (6Mi) : WT5 (80KB, dead before scan) -> Ach|Bch|hst -> BTout
    __hip_bfloat16* Ahl   = (__hip_bfloat16*)(ws);
    float*          xpath = (float*)(ws + 64 * MB);
    __hip_bfloat16* BTin  = (__hip_bfloat16*)(ws + 128 * MB);
    float*          cand  = (float*)(ws + 128 * MB);
    __hip_bfloat16* WT5   = (__hip_bfloat16*)(ws + 192 * MB);
    float*          Ach   = (float*)(ws + 192 * MB);
    float*          Bch   = Ach + 524288;
    float*          hst   = Bch + 524288;
    __hip_bfloat16* BTout = (__hip_bfloat16*)(ws + 192 * MB);
    __hip_bfloat16* Xhl   = (__hip_bfloat16*)(ws);
    __hip_bfloat16* gA    = (__hip_bfloat16*)(ws);
    float*          decay = xpath;
    float*          zsilu = out;   // d_out as scratch until final GEMM

    // 1) conversions
    x_to_a<<<16384, 256, 0, stream>>>(x, Ahl);
    w_to_bt<<<dim3(16, 32), 256, 0, stream>>>(ipw, BTin, 2048);
    w5_to_wt<<<10, 256, 0, stream>>>(bbw, f1w, f2w, tauw, decw, WT5);
    // 2) in_proj GEMM (split-bf16 MFMA) + silu(z)
    mfma_gemm<16, 1><<<2048, 256, 0, stream>>>(Ahl, BTin, xpath, zsilu);
    // 3) conv + silu -> swizzled bf16 hi|lo X
    conv_silu_bf<<<8192, 256, 0, stream>>>(xpath, cw, cb, Xhl);
    // 4) fused MFMA backbone -> cand, decay
    backbone_mfma<<<2048, 256, 0, stream>>>(Xhl, WT5, bbb, f1b, f2b,
                                            taub, taub2, decb, cand, decay);
    // 5) chunked scan -> h (in cand)
    scan_compose<<<2048, 256, 0, stream>>>(decay, cand, Ach, Bch);
    scan_chunks<<<32, 256, 0, stream>>>(Ach, Bch, hst);
    scan_apply<<<2048, 256, 0, stream>>>(decay, cand, hst);
    // 6) out_proj weight conversion (scan scratch dead)
    w_to_bt<<<dim3(16, 16), 256, 0, stream>>>(opw, BTout, 1024);
    // 7) state_out + gate -> bf16 hi|lo
    stateout_gate<<<2048, 256, 0, stream>>>(cand, sow, sob, zsilu, gA);
    // 8) out_proj GEMM
    mfma_gemm<8, 0><<<1024, 256, 0, stream>>>(gA, BTout, out, nullptr);
}

// Round 4
// 599.654 us; speedup vs baseline: 2.8861x; 1.0297x over previous
//
#include <hip/hip_runtime.h>
#include <hip/hip_bf16.h>
#include <math.h>

// Problem constants
#define BN   8
#define SN   2048
#define HN   1024
#define NTOK 16384   // B*S
#define NHD  16
#define HDD  64
#define NSD  64

typedef __attribute__((ext_vector_type(8))) short short8;
typedef __attribute__((ext_vector_type(4))) float f32x4;

__device__ __forceinline__ float fsig(float x)  { return 1.f / (1.f + __expf(-x)); }
__device__ __forceinline__ float fsilu(float x) { return x / (1.f + __expf(-x)); }
__device__ __forceinline__ float ftanh(float x) {
    const float t = __expf(-2.f * fabsf(x));
    const float r = (1.f - t) / (1.f + t);
    return x >= 0.f ? r : -r;
}
__device__ __forceinline__ void hilo(float v, __hip_bfloat16& h, __hip_bfloat16& l) {
    h = __float2bfloat16(v);
    l = __float2bfloat16(v - __bfloat162float(h));
}
__device__ __forceinline__ void gload_lds16(const void* g, void* l) {
    __builtin_amdgcn_global_load_lds(
        (const __attribute__((address_space(1))) unsigned int*)g,
        (__attribute__((address_space(3))) unsigned int*)l, 16, 0, 0);
}

// ---------------------------------------------------------------------------
// x (16384x1024 f32) -> A (16384x2048 bf16): [hi | lo] per row
// ---------------------------------------------------------------------------
__global__ __launch_bounds__(256)
void x_to_a(const float* __restrict__ X, __hip_bfloat16* __restrict__ A)
{
    const int idx = blockIdx.x * 256 + threadIdx.x;   // 4M float4s
    const int r  = idx >> 8;
    const int c4 = (idx & 255) * 4;
    const float4 v = *(const float4*)&X[(size_t)r * 1024 + c4];
    union { ushort4 u; __hip_bfloat16 b[4]; } H, L;
    hilo(v.x, H.b[0], L.b[0]);
    hilo(v.y, H.b[1], L.b[1]);
    hilo(v.z, H.b[2], L.b[2]);
    hilo(v.w, H.b[3], L.b[3]);
    *(ushort4*)&A[(size_t)r * 2048 + c4]        = H.u;
    *(ushort4*)&A[(size_t)r * 2048 + 1024 + c4] = L.u;
}

// ---------------------------------------------------------------------------
// W (1024 x N f32, (in,out)) -> BT (N x 2048 bf16): BT[n][k]=hi(W[k][n]),
// BT[n][1024+k]=lo(W[k][n]).  64x64 LDS-tiled transpose.
// ---------------------------------------------------------------------------
__global__ __launch_bounds__(256)
void w_to_bt(const float* __restrict__ W, __hip_bfloat16* __restrict__ BT, int N)
{
    __shared__ float t[64][65];
    const int k0 = blockIdx.x * 64;
    const int n0 = blockIdx.y * 64;
    const int c  = threadIdx.x & 63, r4 = threadIdx.x >> 6;
#pragma unroll
    for (int rr = 0; rr < 64; rr += 4)
        t[rr + r4][c] = W[(size_t)(k0 + rr + r4) * N + n0 + c];
    __syncthreads();
#pragma unroll
    for (int rr = 0; rr < 64; rr += 4) {
        const float v = t[c][rr + r4];
        __hip_bfloat16 h, l;
        hilo(v, h, l);
        const size_t o = (size_t)(n0 + rr + r4) * 2048 + k0 + c;
        BT[o]        = h;
        BT[o + 1024] = l;
    }
}

// ---------------------------------------------------------------------------
// 5 backbone weight mats (64x64 f32, (k,n)) -> WT5[mat][n][16 chunks x 8 bf16]
// hi octet o at chunk (o ^ (n&15)), lo at ((o|8) ^ (n&15)).  (pre-swizzled)
// ---------------------------------------------------------------------------
__global__ __launch_bounds__(256)
void w5_to_wt(const float* __restrict__ w0, const float* __restrict__ w1,
              const float* __restrict__ w2, const float* __restrict__ w3,
              const float* __restrict__ w4, __hip_bfloat16* __restrict__ WT5)
{
    const int idx = blockIdx.x * 256 + threadIdx.x;
    if (idx >= 2560) return;
    const int o = idx & 7, n = (idx >> 3) & 63, mat = idx >> 9;
    const float* W = mat == 0 ? w0 : mat == 1 ? w1 : mat == 2 ? w2 : mat == 3 ? w3 : w4;
    alignas(16) __hip_bfloat16 hb[8], lb[8];
#pragma unroll
    for (int j = 0; j < 8; ++j) {
        const float v = W[(o * 8 + j) * 64 + n];
        hilo(v, hb[j], lb[j]);
    }
    __hip_bfloat16* row = WT5 + (size_t)(mat * 64 + n) * 128;
    *(short8*)&row[((o     ) ^ (n & 15)) * 8] = *(const short8*)hb;
    *(short8*)&row[((o | 8) ^ (n & 15)) * 8] = *(const short8*)lb;
}

// ---------------------------------------------------------------------------
// MFMA GEMM (split bf16, 3 products): C = Ah*Bh + Ah*Bl + Al*Bh.
// 256x256 tile, BK=32, 8 waves (2Mx4N), double-buffered LDS (128 KB),
// issue-early prefetch, ONE barrier per K-tile (drain lands where depth-1
// prefetch needs it), setprio around MFMA clusters, XCD+chunk swizzles.
// NCT = N/256 col-tiles.  MODE 0: store C (stride NCT*256).
// MODE 1: cols<1024 -> out0 (stride 1024); cols>=1024 -> silu -> out1.
// ---------------------------------------------------------------------------
template<int NCT, int MODE>
__global__ __launch_bounds__(512, 2)
void mfma_gemm256(const __hip_bfloat16* __restrict__ A,
                  const __hip_bfloat16* __restrict__ BT,
                  float* __restrict__ out0, float* __restrict__ out1)
{
    // [buf][mat: Ah,Al,Bh,Bl][256 rows x 32 k]  = 128 KB
    __shared__ __hip_bfloat16 lds[2][4][8192];
    const int tid  = threadIdx.x;
    const int lane = tid & 63, wave = tid >> 6;
    const int wr   = wave >> 2, wc = wave & 3;     // 2 x 4 wave grid
    const int l15  = lane & 15, l4 = lane >> 4;

    // XCD-aware bijective swizzle (gridDim.x % 8 == 0 at both call sites)
    const int nwg = gridDim.x;
    const int cpx = nwg >> 3;
    const int swz = (blockIdx.x & 7) * cpx + (blockIdx.x >> 3);
    const int mt = swz / NCT, nt = swz % NCT;
    const int row0 = mt * 256, col0 = nt * 256;

    // staging thread map: issue i covers mat=i>>1, rows half*128..+127
    const int s_r = tid >> 2;          // 0..127 within half
    const int s_c = tid & 3;           // chunk
    const int s_sc = s_c ^ ((s_r >> 1) & 3);   // pre-swizzled source chunk

    f32x4 acc[8][4];
#pragma unroll
    for (int m = 0; m < 8; ++m)
#pragma unroll
        for (int n = 0; n < 4; ++n) acc[m][n] = (f32x4)0.f;

    const int rdsc = (l4 ^ ((l15 >> 1) & 3)) * 8;   // swizzled read chunk (elems)

    // ---- prologue: stage K-tile 0 into buf 0 ----
#pragma unroll
    for (int i = 0; i < 8; ++i) {
        const int mat = i >> 1, half = i & 1;
        const int r = half * 128 + s_r;
        const __hip_bfloat16* src = (mat < 2)
            ? &A [(size_t)(row0 + r) * 2048 + mat * 1024 + s_sc * 8]
            : &BT[(size_t)(col0 + r) * 2048 + (mat - 2) * 1024 + s_sc * 8];
        gload_lds16(src, &lds[0][mat][r * 32 + s_c * 8]);
    }
    __syncthreads();

#pragma unroll 2
    for (int t = 0; t < 32; ++t) {
        const int cur = t & 1, nxt = cur ^ 1;
        const int kk_next = (t + 1) << 5;
        const bool pf = (t < 31);

#pragma unroll
        for (int p = 0; p < 4; ++p) {
            const int mh = p >> 1, nh = p & 1;

            // issue-early prefetch: 2 of 8 loads for tile t+1
            if (pf) {
#pragma unroll
                for (int i = 2 * p; i < 2 * p + 2; ++i) {
                    const int mat = i >> 1, half = i & 1;
                    const int r = half * 128 + s_r;
                    const __hip_bfloat16* src = (mat < 2)
                        ? &A [(size_t)(row0 + r) * 2048 + mat * 1024 + kk_next + s_sc * 8]
                        : &BT[(size_t)(col0 + r) * 2048 + (mat - 2) * 1024 + kk_next + s_sc * 8];
                    gload_lds16(src, &lds[nxt][mat][r * 32 + s_c * 8]);
                }
            }

            // ds_read this quadrant's fragments from buf cur
            short8 ah[4], al[4], bh2[2], bl2[2];
#pragma unroll
            for (int m = 0; m < 4; ++m) {
                const int off = (wr * 128 + mh * 64 + m * 16 + l15) * 32 + rdsc;
                ah[m] = *(const short8*)&lds[cur][0][off];
                al[m] = *(const short8*)&lds[cur][1][off];
            }
#pragma unroll
            for (int n = 0; n < 2; ++n) {
                const int off = (wc * 64 + nh * 32 + n * 16 + l15) * 32 + rdsc;
                bh2[n] = *(const short8*)&lds[cur][2][off];
                bl2[n] = *(const short8*)&lds[cur][3][off];
            }

            __builtin_amdgcn_s_setprio(1);
#pragma unroll
            for (int m = 0; m < 4; ++m)
#pragma unroll
                for (int n = 0; n < 2; ++n) {
                    f32x4 a = acc[mh * 4 + m][nh * 2 + n];
                    a = __builtin_amdgcn_mfma_f32_16x16x32_bf16(ah[m], bh2[n], a, 0, 0, 0);
                    a = __builtin_amdgcn_mfma_f32_16x16x32_bf16(ah[m], bl2[n], a, 0, 0, 0);
                    a = __builtin_amdgcn_mfma_f32_16x16x32_bf16(al[m], bh2[n], a, 0, 0, 0);
                    acc[mh * 4 + m][nh * 2 + n] = a;
                }
            __builtin_amdgcn_s_setprio(0);
        }
        __syncthreads();   // one drain per K-tile: prefetch complete + reads done
    }

    // epilogue: C/D layout col=lane&15, row=(lane>>4)*4+q
    const int orow = l4 * 4, ocol = l15;
#pragma unroll
    for (int M = 0; M < 8; ++M)
#pragma unroll
        for (int N = 0; N < 4; ++N) {
            const int c = col0 + wc * 64 + N * 16 + ocol;
#pragma unroll
            for (int q = 0; q < 4; ++q) {
                const int r = row0 + wr * 128 + M * 16 + orow + q;
                const float v = acc[M][N][q];
                if (MODE == 0) {
                    out0[(size_t)r * (NCT * 256) + c] = v;
                } else {
                    if (c < 1024) out0[(size_t)r * 1024 + c] = v;
                    else          out1[(size_t)r * 1024 + (c - 1024)] = fsilu(v);
                }
            }
        }
}

// ---------------------------------------------------------------------------
// Depthwise causal conv (K=4) + bias + silu -> X as swizzled bf16 hi|lo rows.
// ---------------------------------------------------------------------------
__global__ __launch_bounds__(256)
void conv_silu_bf(const float* __restrict__ xp, const float* __restrict__ cw,
                  const float* __restrict__ cb, __hip_bfloat16* __restrict__ Xhl)
{
    const int idx = blockIdx.x * 256 + threadIdx.x;   // NTOK*128 octets
    const int g  = idx & 127;
    const int bt = idx >> 7;
    const int t  = bt & (SN - 1);
    const int c0 = g * 8;

    float acc[8];
#pragma unroll
    for (int j = 0; j < 8; ++j) acc[j] = cb[c0 + j];
    float4 cwv[8];
#pragma unroll
    for (int j = 0; j < 8; ++j) cwv[j] = *(const float4*)&cw[(c0 + j) * 4];
    const float* cwf = (const float*)cwv;

#pragma unroll
    for (int k = 0; k < 4; ++k) {
        const int tt = t - 3 + k;
        if (tt >= 0) {
            const float* xr = xp + (((size_t)(bt - 3 + k)) << 10) + c0;
            const float4 u0 = *(const float4*)&xr[0];
            const float4 u1 = *(const float4*)&xr[4];
            const float u[8] = {u0.x, u0.y, u0.z, u0.w, u1.x, u1.y, u1.z, u1.w};
#pragma unroll
            for (int j = 0; j < 8; ++j) acc[j] += cwf[j * 4 + k] * u[j];
        }
    }

    alignas(16) __hip_bfloat16 hb[8], lb[8];
#pragma unroll
    for (int j = 0; j < 8; ++j)
        hilo(fsilu(acc[j]), hb[j], lb[j]);

    const int head = c0 >> 6;
    const int o    = (c0 >> 3) & 7;
    __hip_bfloat16* row = Xhl + ((size_t)bt * 16 + head) * 128;
    *(short8*)&row[((o     ) ^ head) * 8] = *(const short8*)hb;
    *(short8*)&row[((o | 8) ^ head) * 8] = *(const short8*)lb;
}

// ---------------------------------------------------------------------------
// Fused MFMA backbone (unchanged from round 3).
// ---------------------------------------------------------------------------
__global__ __launch_bounds__(256, 1)
void backbone_mfma(const __hip_bfloat16* __restrict__ Xhl,
                   const __hip_bfloat16* __restrict__ WT5,
                   const float* __restrict__ bbb,
                   const float* __restrict__ f1b, const float* __restrict__ f2b,
                   const float* __restrict__ taub, const float* __restrict__ taub2,
                   const float* __restrict__ decb,
                   float* __restrict__ cand, float* __restrict__ decay)
{
    __shared__ __hip_bfloat16 Wl[5 * 64 * 128];   // 80 KB
    __shared__ __hip_bfloat16 Xl[128 * 128];      // 32 KB
    __shared__ __hip_bfloat16 Bb[128 * 128];      // 32 KB
    const int tid  = threadIdx.x;
    const int lane = tid & 63, wave = tid >> 6;
    const int l15  = lane & 15, l4 = lane >> 4;

#pragma unroll
    for (int r = 0; r < 20; ++r) {
        const int blk = r * 4 + wave;
        gload_lds16(WT5 + blk * 512 + lane * 8, Wl + blk * 512);
    }
    const __hip_bfloat16* xsrc = Xhl + (size_t)blockIdx.x * 16384;
#pragma unroll
    for (int r = 0; r < 8; ++r) {
        const int blk = r * 4 + wave;
        gload_lds16(xsrc + blk * 512 + lane * 8, Xl + blk * 512);
    }
    __syncthreads();

    // ---- stage 1 ----
    short8 xa[2][2][2];
#pragma unroll
    for (int mt2 = 0; mt2 < 2; ++mt2)
#pragma unroll
        for (int s = 0; s < 2; ++s)
#pragma unroll
            for (int p = 0; p < 2; ++p) {
                const int ch = ((s * 4 + l4) | (p << 3)) ^ l15;
                xa[mt2][s][p] = *(const short8*)&Xl[(wave * 32 + mt2 * 16 + l15) * 128 + ch * 8];
            }

#pragma unroll
    for (int nt = 0; nt < 4; ++nt) {
        short8 wb[2][2];
#pragma unroll
        for (int s = 0; s < 2; ++s)
#pragma unroll
            for (int p = 0; p < 2; ++p) {
                const int ch = ((s * 4 + l4) | (p << 3)) ^ l15;
                wb[s][p] = *(const short8*)&Wl[(nt * 16 + l15) * 128 + ch * 8];
            }
        f32x4 ac[2] = {(f32x4)0.f, (f32x4)0.f};
#pragma unroll
        for (int mt2 = 0; mt2 < 2; ++mt2)
#pragma unroll
            for (int s = 0; s < 2; ++s) {
                ac[mt2] = __builtin_amdgcn_mfma_f32_16x16x32_bf16(xa[mt2][s][0], wb[s][0], ac[mt2], 0, 0, 0);
                ac[mt2] = __builtin_amdgcn_mfma_f32_16x16x32_bf16(xa[mt2][s][0], wb[s][1], ac[mt2], 0, 0, 0);
                ac[mt2] = __builtin_amdgcn_mfma_f32_16x16x32_bf16(xa[mt2][s][1], wb[s][0], ac[mt2], 0, 0, 0);
            }
        const int col = nt * 16 + l15;
        const float bc = bbb[col];
#pragma unroll
        for (int mt2 = 0; mt2 < 2; ++mt2)
#pragma unroll
            for (int q = 0; q < 4; ++q) {
                const int r15 = l4 * 4 + q;
                const int lr  = wave * 32 + mt2 * 16 + r15;
                const float v = fsilu(ac[mt2][q] + bc);
                __hip_bfloat16 h, l;
                hilo(v, h, l);
                Bb[lr * 128 + (((col >> 3)     ) ^ r15) * 8 + (col & 7)] = h;
                Bb[lr * 128 + (((col >> 3) | 8) ^ r15) * 8 + (col & 7)] = l;
            }
    }
    __syncthreads();

    // ---- stage 2 ----
    short8 ba[2][2][2];
#pragma unroll
    for (int mt2 = 0; mt2 < 2; ++mt2)
#pragma unroll
        for (int s = 0; s < 2; ++s)
#pragma unroll
            for (int p = 0; p < 2; ++p) {
                const int ch = ((s * 4 + l4) | (p << 3)) ^ l15;
                ba[mt2][s][p] = *(const short8*)&Bb[(wave * 32 + mt2 * 16 + l15) * 128 + ch * 8];
            }

#pragma unroll
    for (int nt = 0; nt < 4; ++nt) {
        f32x4 a2[4][2];
#pragma unroll
        for (int m = 0; m < 4; ++m)
#pragma unroll
            for (int mt2 = 0; mt2 < 2; ++mt2) a2[m][mt2] = (f32x4)0.f;

#pragma unroll
        for (int mat = 0; mat < 4; ++mat) {
            short8 w2[2][2];
#pragma unroll
            for (int s = 0; s < 2; ++s)
#pragma unroll
                for (int p = 0; p < 2; ++p) {
                    const int ch = ((s * 4 + l4) | (p << 3)) ^ l15;
                    w2[s][p] = *(const short8*)&Wl[((mat + 1) * 64 + nt * 16 + l15) * 128 + ch * 8];
                }
#pragma unroll
            for (int mt2 = 0; mt2 < 2; ++mt2)
#pragma unroll
                for (int s = 0; s < 2; ++s) {
                    a2[mat][mt2] = __builtin_amdgcn_mfma_f32_16x16x32_bf16(ba[mt2][s][0], w2[s][0], a2[mat][mt2], 0, 0, 0);
                    a2[mat][mt2] = __builtin_amdgcn_mfma_f32_16x16x32_bf16(ba[mt2][s][0], w2[s][1], a2[mat][mt2], 0, 0, 0);
                    a2[mat][mt2] = __builtin_amdgcn_mfma_f32_16x16x32_bf16(ba[mt2][s][1], w2[s][0], a2[mat][mt2], 0, 0, 0);
                }
        }

        const int col = nt * 16 + l15;
        const float b1 = f1b[col], b2 = f2b[col];
        const float b3 = taub[col] + taub2[col], b4 = decb[col];
        const size_t Rbase = (size_t)blockIdx.x * 128 + wave * 32;
#pragma unroll
        for (int mt2 = 0; mt2 < 2; ++mt2)
#pragma unroll
            for (int q = 0; q < 4; ++q) {
                const size_t R = Rbase + mt2 * 16 + l4 * 4 + q;
                const float f1v = ftanh(a2[0][mt2][q] + b1);
                const float f2v = ftanh(a2[1][mt2][q] + b2);
                const float tv  = fsig (a2[2][mt2][q] + b3);
                const float dv  = fsig (a2[3][mt2][q] + b4);
                cand [R * 64 + col] = f1v * (1.f - tv) + f2v * tv;
                decay[R * 64 + col] = dv;
            }
    }
}

// ---------------------------------------------------------------------------
// Chunked scan: h_t = d*h + (1-d)*c over S=2048 (64 chunks x 32).
// ---------------------------------------------------------------------------
__global__ __launch_bounds__(256)
void scan_compose(const float* __restrict__ decay, const float* __restrict__ cand,
                  float* __restrict__ Ach, float* __restrict__ Bch)
{
    const int idx = blockIdx.x * 256 + threadIdx.x;
    const int p  = idx & 1023;
    const int rest = idx >> 10;
    const int ch = rest & 63, b = rest >> 6;
    float A = 1.f, Bv = 0.f;
    const size_t base = ((size_t)(b * SN + ch * 32) << 10) + p;
    for (int t = 0; t < 32; ++t) {
        const float d = decay[base + ((size_t)t << 10)];
        const float c = cand [base + ((size_t)t << 10)];
        A  *= d;
        Bv  = d * Bv + (1.f - d) * c;
    }
    Ach[(ch << 13) + (b << 10) + p] = A;
    Bch[(ch << 13) + (b << 10) + p] = Bv;
}

__global__ __launch_bounds__(256)
void scan_chunks(const float* __restrict__ Ach, const float* __restrict__ Bch,
                 float* __restrict__ hstart)
{
    const int q = blockIdx.x * 256 + threadIdx.x;
    float h = 0.f;
    for (int ch = 0; ch < 64; ++ch) {
        hstart[(ch << 13) + q] = h;
        h = Ach[(ch << 13) + q] * h + Bch[(ch << 13) + q];
    }
}

__global__ __launch_bounds__(256)
void scan_apply(const float* __restrict__ decay, float* __restrict__ candh,
                const float* __restrict__ hstart)
{
    const int idx = blockIdx.x * 256 + threadIdx.x;
    const int p  = idx & 1023;
    const int rest = idx >> 10;
    const int ch = rest & 63, b = rest >> 6;
    float h = hstart[(ch << 13) + (b << 10) + p];
    const size_t base = ((size_t)(b * SN + ch * 32) << 10) + p;
    for (int t = 0; t < 32; ++t) {
        const size_t o = base + ((size_t)t << 10);
        const float d = decay[o];
        const float c = candh[o];
        h = d * h + (1.f - d) * c;
        candh[o] = h;
    }
}

// ---------------------------------------------------------------------------
// state_out matvec + bias, gate with silu(z), emit bf16 hi|lo for out_proj.
// ---------------------------------------------------------------------------
__global__ __launch_bounds__(256)
void stateout_gate(const float* __restrict__ h, const float* __restrict__ sow,
                   const float* __restrict__ sob, const float* __restrict__ zs,
                   __hip_bfloat16* __restrict__ gA)
{
    __shared__ float wl[4096];
    __shared__ float hs[32 * 64];
    const int tid = threadIdx.x;
    for (int i = tid; i < 1024; i += 256)
        ((float4*)wl)[i] = ((const float4*)sow)[i];
    __syncthreads();

    const int j = tid & 63, grp = tid >> 6;
    for (int r = 0; r < 4; ++r) {
        const int base = (blockIdx.x * 4 + r) * 32;
        for (int i = tid; i < 512; i += 256)
            ((float4*)hs)[i] = ((const float4*)(h + (size_t)base * 64))[i];
        __syncthreads();

        float a[8];
        const float bj = sob[j];
#pragma unroll
        for (int g = 0; g < 8; ++g) a[g] = bj;
#pragma unroll 4
        for (int i = 0; i < 64; ++i) {
            const float w = wl[i * 64 + j];
#pragma unroll
            for (int g = 0; g < 8; ++g) a[g] += hs[(grp * 8 + g) * 64 + i] * w;
        }
#pragma unroll
        for (int g = 0; g < 8; ++g) {
            const size_t o = (size_t)(base + grp * 8 + g) * 64 + j;
            const float v = a[g] * zs[o];
            const size_t row = o >> 10, col = o & 1023;
            __hip_bfloat16 hb, lb;
            hilo(v, hb, lb);
            gA[row * 2048 + col]        = hb;
            gA[row * 2048 + 1024 + col] = lb;
        }
        __syncthreads();
    }
}

// ---------------------------------------------------------------------------
extern "C" void kernel_launch(void* const* d_in, const int* in_sizes, int n_in,
                              void* d_out, int out_size, void* d_ws, size_t ws_size,
                              hipStream_t stream)
{
    const float* x     = (const float*)d_in[0];
    const float* ipw   = (const float*)d_in[1];
    const float* cw    = (const float*)d_in[2];
    const float* cb    = (const float*)d_in[3];
    const float* bbw   = (const float*)d_in[4];
    const float* bbb   = (const float*)d_in[5];
    const float* f1w   = (const float*)d_in[6];
    const float* f1b   = (const float*)d_in[7];
    const float* f2w   = (const float*)d_in[8];
    const float* f2b   = (const float*)d_in[9];
    const float* tauw  = (const float*)d_in[10];
    const float* taub  = (const float*)d_in[11];
    const float* taub2 = (const float*)d_in[12];
    const float* decw  = (const float*)d_in[13];
    const float* decb  = (const float*)d_in[14];
    const float* sow   = (const float*)d_in[15];
    const float* sob   = (const float*)d_in[16];
    const float* opw   = (const float*)d_in[17];

    float* out = (float*)d_out;
    char*  ws  = (char*)d_ws;
    const size_t MB = 1024 * 1024;

    // Workspace map (198 MiB):
    //  @0Mi   (64Mi): Ahl (bf16) -> Xhl (bf16, conv out) -> gA (bf16)
    //  @64Mi  (64Mi): xpath (f32) -> decay (f32)
    //  @128Mi (64Mi): BTin (8Mi, dead before cand) -> cand/h (f32)
    //  @192Mi (6Mi) : WT5 (80KB, dead before scan) -> Ach|Bch|hst -> BTout
    __hip_bfloat16* Ahl   = (__hip_bfloat16*)(ws);
    float*          xpath = (float*)(ws + 64 * MB);
    __hip_bfloat16* BTin  = (__hip_bfloat16*)(ws + 128 * MB);
    float*          cand  = (float*)(ws + 128 * MB);
    __hip_bfloat16* WT5   = (__hip_bfloat16*)(ws + 192 * MB);
    float*          Ach   = (float*)(ws + 192 * MB);
    float*          Bch   = Ach + 524288;
    float*          hst   = Bch + 524288;
    __hip_bfloat16* BTout = (__hip_bfloat16*)(ws + 192 * MB);
    __hip_bfloat16* Xhl   = (__hip_bfloat16*)(ws);
    __hip_bfloat16* gA    = (__hip_bfloat16*)(ws);
    float*          decay = xpath;
    float*          zsilu = out;   // d_out as scratch until final GEMM

    // 1) conversions
    x_to_a<<<16384, 256, 0, stream>>>(x, Ahl);
    w_to_bt<<<dim3(16, 32), 256, 0, stream>>>(ipw, BTin, 2048);
    w5_to_wt<<<10, 256, 0, stream>>>(bbw, f1w, f2w, tauw, decw, WT5);
    // 2) in_proj GEMM (split-bf16 MFMA, 256^2 pipelined) + silu(z)
    mfma_gemm256<8, 1><<<512, 512, 0, stream>>>(Ahl, BTin, xpath, zsilu);
    // 3) conv + silu -> swizzled bf16 hi|lo X
    conv_silu_bf<<<8192, 256, 0, stream>>>(xpath, cw, cb, Xhl);
    // 4) fused MFMA backbone -> cand, decay
    backbone_mfma<<<2048, 256, 0, stream>>>(Xhl, WT5, bbb, f1b, f2b,
                                            taub, taub2, decb, cand, decay);
    // 5) chunked scan -> h (in cand)
    scan_compose<<<2048, 256, 0, stream>>>(decay, cand, Ach, Bch);
    scan_chunks<<<32, 256, 0, stream>>>(Ach, Bch, hst);
    scan_apply<<<2048, 256, 0, stream>>>(decay, cand, hst);
    // 6) out_proj weight conversion (scan scratch dead)
    w_to_bt<<<dim3(16, 16), 256, 0, stream>>>(opw, BTout, 1024);
    // 7) state_out + gate -> bf16 hi|lo
    stateout_gate<<<2048, 256, 0, stream>>>(cand, sow, sob, zsilu, gA);
    // 8) out_proj GEMM
    mfma_gemm256<4, 0><<<256, 512, 0, stream>>>(gA, BTout, out, nullptr);
}

// Round 5
// 590.218 us; speedup vs baseline: 2.9323x; 1.0160x over previous
//
#include <hip/hip_runtime.h>
#include <hip/hip_bf16.h>
#include <math.h>

// Problem constants
#define BN   8
#define SN   2048
#define HN   1024
#define NTOK 16384   // B*S
#define NHD  16
#define HDD  64
#define NSD  64

typedef __attribute__((ext_vector_type(8))) short short8;
typedef __attribute__((ext_vector_type(4))) float f32x4;

__device__ __forceinline__ float fsig(float x)  { return 1.f / (1.f + __expf(-x)); }
__device__ __forceinline__ float fsilu(float x) { return x / (1.f + __expf(-x)); }
__device__ __forceinline__ float ftanh(float x) {
    const float t = __expf(-2.f * fabsf(x));
    const float r = (1.f - t) / (1.f + t);
    return x >= 0.f ? r : -r;
}
__device__ __forceinline__ void hilo(float v, __hip_bfloat16& h, __hip_bfloat16& l) {
    h = __float2bfloat16(v);
    l = __float2bfloat16(v - __bfloat162float(h));
}
__device__ __forceinline__ void gload_lds16(const void* g, void* l) {
    __builtin_amdgcn_global_load_lds(
        (const __attribute__((address_space(1))) unsigned int*)g,
        (__attribute__((address_space(3))) unsigned int*)l, 16, 0, 0);
}

// ---------------------------------------------------------------------------
// x (16384x1024 f32) -> A (16384x2048 bf16): [hi | lo] per row
// ---------------------------------------------------------------------------
__global__ __launch_bounds__(256)
void x_to_a(const float* __restrict__ X, __hip_bfloat16* __restrict__ A)
{
    const int idx = blockIdx.x * 256 + threadIdx.x;   // 4M float4s
    const int r  = idx >> 8;
    const int c4 = (idx & 255) * 4;
    const float4 v = *(const float4*)&X[(size_t)r * 1024 + c4];
    union { ushort4 u; __hip_bfloat16 b[4]; } H, L;
    hilo(v.x, H.b[0], L.b[0]);
    hilo(v.y, H.b[1], L.b[1]);
    hilo(v.z, H.b[2], L.b[2]);
    hilo(v.w, H.b[3], L.b[3]);
    *(ushort4*)&A[(size_t)r * 2048 + c4]        = H.u;
    *(ushort4*)&A[(size_t)r * 2048 + 1024 + c4] = L.u;
}

// ---------------------------------------------------------------------------
// W (1024 x N f32, (in,out)) -> BT (N x 2048 bf16): BT[n][k]=hi(W[k][n]),
// BT[n][1024+k]=lo(W[k][n]).  64x64 LDS-tiled transpose.
// ---------------------------------------------------------------------------
__global__ __launch_bounds__(256)
void w_to_bt(const float* __restrict__ W, __hip_bfloat16* __restrict__ BT, int N)
{
    __shared__ float t[64][65];
    const int k0 = blockIdx.x * 64;
    const int n0 = blockIdx.y * 64;
    const int c  = threadIdx.x & 63, r4 = threadIdx.x >> 6;
#pragma unroll
    for (int rr = 0; rr < 64; rr += 4)
        t[rr + r4][c] = W[(size_t)(k0 + rr + r4) * N + n0 + c];
    __syncthreads();
#pragma unroll
    for (int rr = 0; rr < 64; rr += 4) {
        const float v = t[c][rr + r4];
        __hip_bfloat16 h, l;
        hilo(v, h, l);
        const size_t o = (size_t)(n0 + rr + r4) * 2048 + k0 + c;
        BT[o]        = h;
        BT[o + 1024] = l;
    }
}

// ---------------------------------------------------------------------------
// 5 backbone weight mats (64x64 f32, (k,n)) -> WT5[mat][n][16 chunks x 8 bf16]
// hi octet o at chunk (o ^ (n&15)), lo at ((o|8) ^ (n&15)).  (pre-swizzled)
// ---------------------------------------------------------------------------
__global__ __launch_bounds__(256)
void w5_to_wt(const float* __restrict__ w0, const float* __restrict__ w1,
              const float* __restrict__ w2, const float* __restrict__ w3,
              const float* __restrict__ w4, __hip_bfloat16* __restrict__ WT5)
{
    const int idx = blockIdx.x * 256 + threadIdx.x;
    if (idx >= 2560) return;
    const int o = idx & 7, n = (idx >> 3) & 63, mat = idx >> 9;
    const float* W = mat == 0 ? w0 : mat == 1 ? w1 : mat == 2 ? w2 : mat == 3 ? w3 : w4;
    alignas(16) __hip_bfloat16 hb[8], lb[8];
#pragma unroll
    for (int j = 0; j < 8; ++j) {
        const float v = W[(o * 8 + j) * 64 + n];
        hilo(v, hb[j], lb[j]);
    }
    __hip_bfloat16* row = WT5 + (size_t)(mat * 64 + n) * 128;
    *(short8*)&row[((o     ) ^ (n & 15)) * 8] = *(const short8*)hb;
    *(short8*)&row[((o | 8) ^ (n & 15)) * 8] = *(const short8*)lb;
}

// ---------------------------------------------------------------------------
// MFMA GEMM (split bf16, 3 products): C = Ah*Bh + Ah*Bl + Al*Bh.
// 256x256 tile, BK=32, 8 waves (2Mx4N), double-buffered LDS (128 KB),
// issue-early prefetch, ONE barrier per K-tile, setprio around MFMA,
// XCD+chunk swizzles.  A-frags held across both nh sub-phases (32 ds_reads
// per K-tile instead of 48 -> LDS traffic hides under MFMA).
// ---------------------------------------------------------------------------
template<int NCT, int MODE>
__global__ __launch_bounds__(512, 2)
void mfma_gemm256(const __hip_bfloat16* __restrict__ A,
                  const __hip_bfloat16* __restrict__ BT,
                  float* __restrict__ out0, float* __restrict__ out1)
{
    // [buf][mat: Ah,Al,Bh,Bl][256 rows x 32 k]  = 128 KB
    __shared__ __hip_bfloat16 lds[2][4][8192];
    const int tid  = threadIdx.x;
    const int lane = tid & 63, wave = tid >> 6;
    const int wr   = wave >> 2, wc = wave & 3;     // 2 x 4 wave grid
    const int l15  = lane & 15, l4 = lane >> 4;

    // XCD-aware bijective swizzle (gridDim.x % 8 == 0 at both call sites)
    const int nwg = gridDim.x;
    const int cpx = nwg >> 3;
    const int swz = (blockIdx.x & 7) * cpx + (blockIdx.x >> 3);
    const int mt = swz / NCT, nt = swz % NCT;
    const int row0 = mt * 256, col0 = nt * 256;

    // staging thread map: issue i covers mat=i>>1, rows half*128..+127
    const int s_r = tid >> 2;          // 0..127 within half
    const int s_c = tid & 3;           // chunk
    const int s_sc = s_c ^ ((s_r >> 1) & 3);   // pre-swizzled source chunk

    f32x4 acc[8][4];
#pragma unroll
    for (int m = 0; m < 8; ++m)
#pragma unroll
        for (int n = 0; n < 4; ++n) acc[m][n] = (f32x4)0.f;

    const int rdsc = (l4 ^ ((l15 >> 1) & 3)) * 8;   // swizzled read chunk (elems)

    // ---- prologue: stage K-tile 0 into buf 0 ----
#pragma unroll
    for (int i = 0; i < 8; ++i) {
        const int mat = i >> 1, half = i & 1;
        const int r = half * 128 + s_r;
        const __hip_bfloat16* src = (mat < 2)
            ? &A [(size_t)(row0 + r) * 2048 + mat * 1024 + s_sc * 8]
            : &BT[(size_t)(col0 + r) * 2048 + (mat - 2) * 1024 + s_sc * 8];
        gload_lds16(src, &lds[0][mat][r * 32 + s_c * 8]);
    }
    __syncthreads();

#pragma unroll 2
    for (int t = 0; t < 32; ++t) {
        const int cur = t & 1, nxt = cur ^ 1;
        const int kk_next = (t + 1) << 5;
        const bool pf = (t < 31);

#pragma unroll
        for (int mh = 0; mh < 2; ++mh) {
            // A-frags for this mh: read once, reuse across both nh sub-phases
            short8 ah[4], al[4];
#pragma unroll
            for (int m = 0; m < 4; ++m) {
                const int off = (wr * 128 + mh * 64 + m * 16 + l15) * 32 + rdsc;
                ah[m] = *(const short8*)&lds[cur][0][off];
                al[m] = *(const short8*)&lds[cur][1][off];
            }

#pragma unroll
            for (int nh = 0; nh < 2; ++nh) {
                const int p = mh * 2 + nh;
                // issue-early prefetch: 2 of 8 loads for tile t+1
                if (pf) {
#pragma unroll
                    for (int i = 2 * p; i < 2 * p + 2; ++i) {
                        const int mat = i >> 1, half = i & 1;
                        const int r = half * 128 + s_r;
                        const __hip_bfloat16* src = (mat < 2)
                            ? &A [(size_t)(row0 + r) * 2048 + mat * 1024 + kk_next + s_sc * 8]
                            : &BT[(size_t)(col0 + r) * 2048 + (mat - 2) * 1024 + kk_next + s_sc * 8];
                        gload_lds16(src, &lds[nxt][mat][r * 32 + s_c * 8]);
                    }
                }

                short8 bh2[2], bl2[2];
#pragma unroll
                for (int n = 0; n < 2; ++n) {
                    const int off = (wc * 64 + nh * 32 + n * 16 + l15) * 32 + rdsc;
                    bh2[n] = *(const short8*)&lds[cur][2][off];
                    bl2[n] = *(const short8*)&lds[cur][3][off];
                }

                __builtin_amdgcn_s_setprio(1);
#pragma unroll
                for (int m = 0; m < 4; ++m)
#pragma unroll
                    for (int n = 0; n < 2; ++n) {
                        f32x4 a = acc[mh * 4 + m][nh * 2 + n];
                        a = __builtin_amdgcn_mfma_f32_16x16x32_bf16(ah[m], bh2[n], a, 0, 0, 0);
                        a = __builtin_amdgcn_mfma_f32_16x16x32_bf16(ah[m], bl2[n], a, 0, 0, 0);
                        a = __builtin_amdgcn_mfma_f32_16x16x32_bf16(al[m], bh2[n], a, 0, 0, 0);
                        acc[mh * 4 + m][nh * 2 + n] = a;
                    }
                __builtin_amdgcn_s_setprio(0);
            }
        }
        __syncthreads();   // one drain per K-tile: prefetch complete + reads done
    }

    // epilogue: C/D layout col=lane&15, row=(lane>>4)*4+q
    const int orow = l4 * 4, ocol = l15;
#pragma unroll
    for (int M = 0; M < 8; ++M)
#pragma unroll
        for (int N = 0; N < 4; ++N) {
            const int c = col0 + wc * 64 + N * 16 + ocol;
#pragma unroll
            for (int q = 0; q < 4; ++q) {
                const int r = row0 + wr * 128 + M * 16 + orow + q;
                const float v = acc[M][N][q];
                if (MODE == 0) {
                    out0[(size_t)r * (NCT * 256) + c] = v;
                } else {
                    if (c < 1024) out0[(size_t)r * 1024 + c] = v;
                    else          out1[(size_t)r * 1024 + (c - 1024)] = fsilu(v);
                }
            }
        }
}

// ---------------------------------------------------------------------------
// Depthwise causal conv (K=4) + bias + silu -> X as swizzled bf16 hi|lo rows.
// ---------------------------------------------------------------------------
__global__ __launch_bounds__(256)
void conv_silu_bf(const float* __restrict__ xp, const float* __restrict__ cw,
                  const float* __restrict__ cb, __hip_bfloat16* __restrict__ Xhl)
{
    const int idx = blockIdx.x * 256 + threadIdx.x;   // NTOK*128 octets
    const int g  = idx & 127;
    const int bt = idx >> 7;
    const int t  = bt & (SN - 1);
    const int c0 = g * 8;

    float acc[8];
#pragma unroll
    for (int j = 0; j < 8; ++j) acc[j] = cb[c0 + j];
    float4 cwv[8];
#pragma unroll
    for (int j = 0; j < 8; ++j) cwv[j] = *(const float4*)&cw[(c0 + j) * 4];
    const float* cwf = (const float*)cwv;

#pragma unroll
    for (int k = 0; k < 4; ++k) {
        const int tt = t - 3 + k;
        if (tt >= 0) {
            const float* xr = xp + (((size_t)(bt - 3 + k)) << 10) + c0;
            const float4 u0 = *(const float4*)&xr[0];
            const float4 u1 = *(const float4*)&xr[4];
            const float u[8] = {u0.x, u0.y, u0.z, u0.w, u1.x, u1.y, u1.z, u1.w};
#pragma unroll
            for (int j = 0; j < 8; ++j) acc[j] += cwf[j * 4 + k] * u[j];
        }
    }

    alignas(16) __hip_bfloat16 hb[8], lb[8];
#pragma unroll
    for (int j = 0; j < 8; ++j)
        hilo(fsilu(acc[j]), hb[j], lb[j]);

    const int head = c0 >> 6;
    const int o    = (c0 >> 3) & 7;
    __hip_bfloat16* row = Xhl + ((size_t)bt * 16 + head) * 128;
    *(short8*)&row[((o     ) ^ head) * 8] = *(const short8*)hb;
    *(short8*)&row[((o | 8) ^ head) * 8] = *(const short8*)lb;
}

// ---------------------------------------------------------------------------
// Fused MFMA backbone (unchanged from round 3).
// ---------------------------------------------------------------------------
__global__ __launch_bounds__(256, 1)
void backbone_mfma(const __hip_bfloat16* __restrict__ Xhl,
                   const __hip_bfloat16* __restrict__ WT5,
                   const float* __restrict__ bbb,
                   const float* __restrict__ f1b, const float* __restrict__ f2b,
                   const float* __restrict__ taub, const float* __restrict__ taub2,
                   const float* __restrict__ decb,
                   float* __restrict__ cand, float* __restrict__ decay)
{
    __shared__ __hip_bfloat16 Wl[5 * 64 * 128];   // 80 KB
    __shared__ __hip_bfloat16 Xl[128 * 128];      // 32 KB
    __shared__ __hip_bfloat16 Bb[128 * 128];      // 32 KB
    const int tid  = threadIdx.x;
    const int lane = tid & 63, wave = tid >> 6;
    const int l15  = lane & 15, l4 = lane >> 4;

#pragma unroll
    for (int r = 0; r < 20; ++r) {
        const int blk = r * 4 + wave;
        gload_lds16(WT5 + blk * 512 + lane * 8, Wl + blk * 512);
    }
    const __hip_bfloat16* xsrc = Xhl + (size_t)blockIdx.x * 16384;
#pragma unroll
    for (int r = 0; r < 8; ++r) {
        const int blk = r * 4 + wave;
        gload_lds16(xsrc + blk * 512 + lane * 8, Xl + blk * 512);
    }
    __syncthreads();

    // ---- stage 1 ----
    short8 xa[2][2][2];
#pragma unroll
    for (int mt2 = 0; mt2 < 2; ++mt2)
#pragma unroll
        for (int s = 0; s < 2; ++s)
#pragma unroll
            for (int p = 0; p < 2; ++p) {
                const int ch = ((s * 4 + l4) | (p << 3)) ^ l15;
                xa[mt2][s][p] = *(const short8*)&Xl[(wave * 32 + mt2 * 16 + l15) * 128 + ch * 8];
            }

#pragma unroll
    for (int nt = 0; nt < 4; ++nt) {
        short8 wb[2][2];
#pragma unroll
        for (int s = 0; s < 2; ++s)
#pragma unroll
            for (int p = 0; p < 2; ++p) {
                const int ch = ((s * 4 + l4) | (p << 3)) ^ l15;
                wb[s][p] = *(const short8*)&Wl[(nt * 16 + l15) * 128 + ch * 8];
            }
        f32x4 ac[2] = {(f32x4)0.f, (f32x4)0.f};
#pragma unroll
        for (int mt2 = 0; mt2 < 2; ++mt2)
#pragma unroll
            for (int s = 0; s < 2; ++s) {
                ac[mt2] = __builtin_amdgcn_mfma_f32_16x16x32_bf16(xa[mt2][s][0], wb[s][0], ac[mt2], 0, 0, 0);
                ac[mt2] = __builtin_amdgcn_mfma_f32_16x16x32_bf16(xa[mt2][s][0], wb[s][1], ac[mt2], 0, 0, 0);
                ac[mt2] = __builtin_amdgcn_mfma_f32_16x16x32_bf16(xa[mt2][s][1], wb[s][0], ac[mt2], 0, 0, 0);
            }
        const int col = nt * 16 + l15;
        const float bc = bbb[col];
#pragma unroll
        for (int mt2 = 0; mt2 < 2; ++mt2)
#pragma unroll
            for (int q = 0; q < 4; ++q) {
                const int r15 = l4 * 4 + q;
                const int lr  = wave * 32 + mt2 * 16 + r15;
                const float v = fsilu(ac[mt2][q] + bc);
                __hip_bfloat16 h, l;
                hilo(v, h, l);
                Bb[lr * 128 + (((col >> 3)     ) ^ r15) * 8 + (col & 7)] = h;
                Bb[lr * 128 + (((col >> 3) | 8) ^ r15) * 8 + (col & 7)] = l;
            }
    }
    __syncthreads();

    // ---- stage 2 ----
    short8 ba[2][2][2];
#pragma unroll
    for (int mt2 = 0; mt2 < 2; ++mt2)
#pragma unroll
        for (int s = 0; s < 2; ++s)
#pragma unroll
            for (int p = 0; p < 2; ++p) {
                const int ch = ((s * 4 + l4) | (p << 3)) ^ l15;
                ba[mt2][s][p] = *(const short8*)&Bb[(wave * 32 + mt2 * 16 + l15) * 128 + ch * 8];
            }

#pragma unroll
    for (int nt = 0; nt < 4; ++nt) {
        f32x4 a2[4][2];
#pragma unroll
        for (int m = 0; m < 4; ++m)
#pragma unroll
            for (int mt2 = 0; mt2 < 2; ++mt2) a2[m][mt2] = (f32x4)0.f;

#pragma unroll
        for (int mat = 0; mat < 4; ++mat) {
            short8 w2[2][2];
#pragma unroll
            for (int s = 0; s < 2; ++s)
#pragma unroll
                for (int p = 0; p < 2; ++p) {
                    const int ch = ((s * 4 + l4) | (p << 3)) ^ l15;
                    w2[s][p] = *(const short8*)&Wl[((mat + 1) * 64 + nt * 16 + l15) * 128 + ch * 8];
                }
#pragma unroll
            for (int mt2 = 0; mt2 < 2; ++mt2)
#pragma unroll
                for (int s = 0; s < 2; ++s) {
                    a2[mat][mt2] = __builtin_amdgcn_mfma_f32_16x16x32_bf16(ba[mt2][s][0], w2[s][0], a2[mat][mt2], 0, 0, 0);
                    a2[mat][mt2] = __builtin_amdgcn_mfma_f32_16x16x32_bf16(ba[mt2][s][0], w2[s][1], a2[mat][mt2], 0, 0, 0);
                    a2[mat][mt2] = __builtin_amdgcn_mfma_f32_16x16x32_bf16(ba[mt2][s][1], w2[s][0], a2[mat][mt2], 0, 0, 0);
                }
        }

        const int col = nt * 16 + l15;
        const float b1 = f1b[col], b2 = f2b[col];
        const float b3 = taub[col] + taub2[col], b4 = decb[col];
        const size_t Rbase = (size_t)blockIdx.x * 128 + wave * 32;
#pragma unroll
        for (int mt2 = 0; mt2 < 2; ++mt2)
#pragma unroll
            for (int q = 0; q < 4; ++q) {
                const size_t R = Rbase + mt2 * 16 + l4 * 4 + q;
                const float f1v = ftanh(a2[0][mt2][q] + b1);
                const float f2v = ftanh(a2[1][mt2][q] + b2);
                const float tv  = fsig (a2[2][mt2][q] + b3);
                const float dv  = fsig (a2[3][mt2][q] + b4);
                cand [R * 64 + col] = f1v * (1.f - tv) + f2v * tv;
                decay[R * 64 + col] = dv;
            }
    }
}

// ---------------------------------------------------------------------------
// Chunked scan: h_t = d*h + (1-d)*c over S=2048 (64 chunks x 32).
// ---------------------------------------------------------------------------
__global__ __launch_bounds__(256)
void scan_compose(const float* __restrict__ decay, const float* __restrict__ cand,
                  float* __restrict__ Ach, float* __restrict__ Bch)
{
    const int idx = blockIdx.x * 256 + threadIdx.x;
    const int p  = idx & 1023;
    const int rest = idx >> 10;
    const int ch = rest & 63, b = rest >> 6;
    float A = 1.f, Bv = 0.f;
    const size_t base = ((size_t)(b * SN + ch * 32) << 10) + p;
    for (int t = 0; t < 32; ++t) {
        const float d = decay[base + ((size_t)t << 10)];
        const float c = cand [base + ((size_t)t << 10)];
        A  *= d;
        Bv  = d * Bv + (1.f - d) * c;
    }
    Ach[(ch << 13) + (b << 10) + p] = A;
    Bch[(ch << 13) + (b << 10) + p] = Bv;
}

__global__ __launch_bounds__(256)
void scan_chunks(const float* __restrict__ Ach, const float* __restrict__ Bch,
                 float* __restrict__ hstart)
{
    const int q = blockIdx.x * 256 + threadIdx.x;
    float h = 0.f;
    for (int ch = 0; ch < 64; ++ch) {
        hstart[(ch << 13) + q] = h;
        h = Ach[(ch << 13) + q] * h + Bch[(ch << 13) + q];
    }
}

// ---------------------------------------------------------------------------
// scan_apply: final h per timestep, emitted directly as swizzled bf16 hi|lo
// rows (same format as Xhl) for the MFMA state_out kernel.  Hhl ALIASES the
// decay buffer: safe because each (token,head) 256B window is read (d) and
// then written by exactly one wave, and the store's data depends on the load.
// ---------------------------------------------------------------------------
__global__ __launch_bounds__(256)
void scan_apply(const float* decay, const float* __restrict__ cand,
                const float* __restrict__ hstart, __hip_bfloat16* Hhl)
{
    const int idx = blockIdx.x * 256 + threadIdx.x;
    const int p  = idx & 1023;
    const int rest = idx >> 10;
    const int ch = rest & 63, b = rest >> 6;
    const int nh = p >> 6, ns = p & 63;
    const int hoff = (((ns >> 3)    ) ^ nh) * 8 + (ns & 7);
    const int loff = (((ns >> 3) | 8) ^ nh) * 8 + (ns & 7);
    float h = hstart[(ch << 13) + (b << 10) + p];
    const int t0 = b * SN + ch * 32;
    const size_t base = ((size_t)t0 << 10) + p;
    for (int t = 0; t < 32; ++t) {
        const size_t o = base + ((size_t)t << 10);
        const float d = decay[o];
        const float c = cand[o];
        h = d * h + (1.f - d) * c;
        __hip_bfloat16 hb, lb;
        hilo(h, hb, lb);
        const size_t row = ((size_t)(t0 + t) * 16 + nh) * 128;
        Hhl[row + hoff] = hb;
        Hhl[row + loff] = lb;
    }
}

// ---------------------------------------------------------------------------
// MFMA state_out: out = H @ sow + sob, gated by silu(z) (precomputed f32),
// emitted as bf16 hi|lo rows for out_proj.  Reuses backbone stage-1 layout.
// sow converted to swizzled hi|lo bf16 in-LDS at kernel start.
// ---------------------------------------------------------------------------
__global__ __launch_bounds__(256)
void stateout_mfma(const __hip_bfloat16* __restrict__ Hhl,
                   const float* __restrict__ sow, const float* __restrict__ sob,
                   const float* __restrict__ zs, __hip_bfloat16* __restrict__ gA)
{
    __shared__ __hip_bfloat16 Wl[64 * 128];   // 16 KB
    __shared__ __hip_bfloat16 Hl[128 * 128];  // 32 KB
    const int tid  = threadIdx.x;
    const int lane = tid & 63, wave = tid >> 6;
    const int l15  = lane & 15, l4 = lane >> 4;

    // convert sow (64x64 f32, (k,n)) -> Wl[n][chunks], chunk-XOR swizzled
    {
        const int n = tid & 63;
        const int ob = (tid >> 6) * 2;
#pragma unroll
        for (int oo = 0; oo < 2; ++oo) {
            const int o = ob + oo;
#pragma unroll
            for (int j = 0; j < 8; ++j) {
                const float v = sow[(o * 8 + j) * 64 + n];
                __hip_bfloat16 hb, lb;
                hilo(v, hb, lb);
                Wl[n * 128 + ((o       ^ (n & 15)) * 8 + j)] = hb;
                Wl[n * 128 + (((o | 8) ^ (n & 15)) * 8 + j)] = lb;
            }
        }
    }
    // stage H tile (128 rows x 128): 2048 chunks, 8 rounds
    const __hip_bfloat16* hsrc = Hhl + (size_t)blockIdx.x * 16384;
#pragma unroll
    for (int r = 0; r < 8; ++r) {
        const int blk = r * 4 + wave;
        gload_lds16(hsrc + blk * 512 + lane * 8, Hl + blk * 512);
    }
    __syncthreads();

    short8 ha[2][2][2];
#pragma unroll
    for (int mt2 = 0; mt2 < 2; ++mt2)
#pragma unroll
        for (int s = 0; s < 2; ++s)
#pragma unroll
            for (int p = 0; p < 2; ++p) {
                const int ch = ((s * 4 + l4) | (p << 3)) ^ l15;
                ha[mt2][s][p] = *(const short8*)&Hl[(wave * 32 + mt2 * 16 + l15) * 128 + ch * 8];
            }

#pragma unroll
    for (int nt = 0; nt < 4; ++nt) {
        short8 wb[2][2];
#pragma unroll
        for (int s = 0; s < 2; ++s)
#pragma unroll
            for (int p = 0; p < 2; ++p) {
                const int ch = ((s * 4 + l4) | (p << 3)) ^ l15;
                wb[s][p] = *(const short8*)&Wl[(nt * 16 + l15) * 128 + ch * 8];
            }
        f32x4 ac[2] = {(f32x4)0.f, (f32x4)0.f};
#pragma unroll
        for (int mt2 = 0; mt2 < 2; ++mt2)
#pragma unroll
            for (int s = 0; s < 2; ++s) {
                ac[mt2] = __builtin_amdgcn_mfma_f32_16x16x32_bf16(ha[mt2][s][0], wb[s][0], ac[mt2], 0, 0, 0);
                ac[mt2] = __builtin_amdgcn_mfma_f32_16x16x32_bf16(ha[mt2][s][0], wb[s][1], ac[mt2], 0, 0, 0);
                ac[mt2] = __builtin_amdgcn_mfma_f32_16x16x32_bf16(ha[mt2][s][1], wb[s][0], ac[mt2], 0, 0, 0);
            }
        const int col = nt * 16 + l15;
        const float bj = sob[col];
#pragma unroll
        for (int mt2 = 0; mt2 < 2; ++mt2)
#pragma unroll
            for (int q = 0; q < 4; ++q) {
                const size_t th = (size_t)blockIdx.x * 128 + wave * 32 + mt2 * 16 + l4 * 4 + q;
                const float v = (ac[mt2][q] + bj) * zs[th * 64 + col];
                __hip_bfloat16 hb, lb;
                hilo(v, hb, lb);
                const size_t token = th >> 4;
                const int colg = (int)(th & 15) * 64 + col;
                gA[token * 2048 + colg]        = hb;
                gA[token * 2048 + 1024 + colg] = lb;
            }
    }
}

// ---------------------------------------------------------------------------
extern "C" void kernel_launch(void* const* d_in, const int* in_sizes, int n_in,
                              void* d_out, int out_size, void* d_ws, size_t ws_size,
                              hipStream_t stream)
{
    const float* x     = (const float*)d_in[0];
    const float* ipw   = (const float*)d_in[1];
    const float* cw    = (const float*)d_in[2];
    const float* cb    = (const float*)d_in[3];
    const float* bbw   = (const float*)d_in[4];
    const float* bbb   = (const float*)d_in[5];
    const float* f1w   = (const float*)d_in[6];
    const float* f1b   = (const float*)d_in[7];
    const float* f2w   = (const float*)d_in[8];
    const float* f2b   = (const float*)d_in[9];
    const float* tauw  = (const float*)d_in[10];
    const float* taub  = (const float*)d_in[11];
    const float* taub2 = (const float*)d_in[12];
    const float* decw  = (const float*)d_in[13];
    const float* decb  = (const float*)d_in[14];
    const float* sow   = (const float*)d_in[15];
    const float* sob   = (const float*)d_in[16];
    const float* opw   = (const float*)d_in[17];

    float* out = (float*)d_out;
    char*  ws  = (char*)d_ws;
    const size_t MB = 1024 * 1024;

    // Workspace map (198 MiB):
    //  @0Mi   (64Mi): Ahl (bf16) -> Xhl (bf16, conv out) -> gA (bf16)
    //  @64Mi  (64Mi): xpath (f32) -> decay (f32) -> Hhl (bf16, in place)
    //  @128Mi (64Mi): BTin (8Mi, dead before cand) -> cand (f32)
    //  @192Mi (6Mi) : WT5 (80KB, dead before scan) -> Ach|Bch|hst -> BTout
    __hip_bfloat16* Ahl   = (__hip_bfloat16*)(ws);
    float*          xpath = (float*)(ws + 64 * MB);
    __hip_bfloat16* BTin  = (__hip_bfloat16*)(ws + 128 * MB);
    float*          cand  = (float*)(ws + 128 * MB);
    __hip_bfloat16* WT5   = (__hip_bfloat16*)(ws + 192 * MB);
    float*          Ach   = (float*)(ws + 192 * MB);
    float*          Bch   = Ach + 524288;
    float*          hst   = Bch + 524288;
    __hip_bfloat16* BTout = (__hip_bfloat16*)(ws + 192 * MB);
    __hip_bfloat16* Xhl   = (__hip_bfloat16*)(ws);
    __hip_bfloat16* gA    = (__hip_bfloat16*)(ws);
    float*          decay = xpath;
    __hip_bfloat16* Hhl   = (__hip_bfloat16*)(ws + 64 * MB);   // aliases decay
    float*          zsilu = out;   // d_out as scratch until final GEMM

    // 1) conversions
    x_to_a<<<16384, 256, 0, stream>>>(x, Ahl);
    w_to_bt<<<dim3(16, 32), 256, 0, stream>>>(ipw, BTin, 2048);
    w5_to_wt<<<10, 256, 0, stream>>>(bbw, f1w, f2w, tauw, decw, WT5);
    // 2) in_proj GEMM (split-bf16 MFMA, 256^2 pipelined) + silu(z)
    mfma_gemm256<8, 1><<<512, 512, 0, stream>>>(Ahl, BTin, xpath, zsilu);
    // 3) conv + silu -> swizzled bf16 hi|lo X
    conv_silu_bf<<<8192, 256, 0, stream>>>(xpath, cw, cb, Xhl);
    // 4) fused MFMA backbone -> cand, decay
    backbone_mfma<<<2048, 256, 0, stream>>>(Xhl, WT5, bbb, f1b, f2b,
                                            taub, taub2, decb, cand, decay);
    // 5) chunked scan -> Hhl (bf16 hi|lo, in decay's storage)
    scan_compose<<<2048, 256, 0, stream>>>(decay, cand, Ach, Bch);
    scan_chunks<<<32, 256, 0, stream>>>(Ach, Bch, hst);
    scan_apply<<<2048, 256, 0, stream>>>(decay, cand, hst, Hhl);
    // 6) out_proj weight conversion (scan scratch dead)
    w_to_bt<<<dim3(16, 16), 256, 0, stream>>>(opw, BTout, 1024);
    // 7) state_out + gate (MFMA) -> bf16 hi|lo
    stateout_mfma<<<2048, 256, 0, stream>>>(Hhl, sow, sob, zsilu, gA);
    // 8) out_proj GEMM
    mfma_gemm256<4, 0><<<256, 512, 0, stream>>>(gA, BTout, out, nullptr);
}